// Round 8
// baseline (1016.871 us; speedup 1.0000x reference)
//
#include <hip/hip_runtime.h>
#include <cstdint>
#include <cstddef>

#define T_SEQ 2048
#define DM    1024
#define HK    256
#define HV    512
#define NH    4
#define KDIM  1024
#define VDIM  2048

typedef __attribute__((ext_vector_type(8))) short bf16x8;
typedef __attribute__((ext_vector_type(4))) float f32x4;
#define AS1 __attribute__((address_space(1)))
#define AS3 __attribute__((address_space(3)))

// ---------------- f32 -> (hi, lo) bf16 split (RNE) ---------------------------
static __device__ inline unsigned short f2bf(float f) {
  unsigned u = __float_as_uint(f);
  unsigned rnd = 0x7fffu + ((u >> 16) & 1u);
  return (unsigned short)((u + rnd) >> 16);
}
static __device__ inline float bf2f(unsigned short h) {
  unsigned u = ((unsigned)h) << 16;
  return __uint_as_float(u);
}

// -------- fused hi/lo casts for x and all 5 weights (one launch) -------------
// grid 16384: [0,8192) x | [8192,9216) Wq | [9216,10240) Wk | [10240,12288) Wv
// | [12288,14336) Wg | [14336,16384) Wo. Routing is block-uniform.
__global__ __launch_bounds__(256) void cast_all(const float* __restrict__ x,
                                                const float* __restrict__ Wq,
                                                const float* __restrict__ Wk,
                                                const float* __restrict__ Wv,
                                                const float* __restrict__ Wg,
                                                const float* __restrict__ Wo,
                                                unsigned short* __restrict__ xh,  unsigned short* __restrict__ xl,
                                                unsigned short* __restrict__ wqh, unsigned short* __restrict__ wql,
                                                unsigned short* __restrict__ wkh, unsigned short* __restrict__ wkl,
                                                unsigned short* __restrict__ wvh, unsigned short* __restrict__ wvl,
                                                unsigned short* __restrict__ wgh, unsigned short* __restrict__ wgl,
                                                unsigned short* __restrict__ woh, unsigned short* __restrict__ wol) {
  const int bx = blockIdx.x;
  const float* in; unsigned short* hi; unsigned short* lo; int rel;
  if (bx < 8192)       { in = x;  hi = xh;  lo = xl;  rel = bx; }
  else if (bx < 9216)  { in = Wq; hi = wqh; lo = wql; rel = bx - 8192; }
  else if (bx < 10240) { in = Wk; hi = wkh; lo = wkl; rel = bx - 9216; }
  else if (bx < 12288) { in = Wv; hi = wvh; lo = wvl; rel = bx - 10240; }
  else if (bx < 14336) { in = Wg; hi = wgh; lo = wgl; rel = bx - 12288; }
  else                 { in = Wo; hi = woh; lo = wol; rel = bx - 14336; }
  int i = rel * 256 + threadIdx.x;          // all segments are exact multiples
  float4 v = ((const float4*)in)[i];
  ushort4 h, l;
  h.x = f2bf(v.x); l.x = f2bf(v.x - bf2f(h.x));
  h.y = f2bf(v.y); l.y = f2bf(v.y - bf2f(h.y));
  h.z = f2bf(v.z); l.z = f2bf(v.z - bf2f(h.z));
  h.w = f2bf(v.w); l.w = f2bf(v.w - bf2f(h.w));
  ((ushort4*)hi)[i] = h;
  ((ushort4*)lo)[i] = l;
}

// -------- split-precision bf16 MFMA GEMM: C = A @ W^T, A=Ah+Al, W=Wh+Wl ------
// C ~= Ah*Wh + Ah*Wl + Al*Wh (f32 accumulate; lo*lo term ~2^-16 rel, dropped).
// 128x128 tile, BK=32, 4 waves 2x2, wave = 64x64 = 4x4 16x16x32 frags.
__global__ __launch_bounds__(256) void gemm_bf16s(const unsigned short* __restrict__ Ah,
                                                  const unsigned short* __restrict__ Al,
                                                  const unsigned short* __restrict__ Wh,
                                                  const unsigned short* __restrict__ Wl,
                                                  float* __restrict__ C,
                                                  int M, int N, int K) {
  __shared__ unsigned short AhS[128 * 32];
  __shared__ unsigned short AlS[128 * 32];
  __shared__ unsigned short WhS[128 * 32];
  __shared__ unsigned short WlS[128 * 32];
  const int t = threadIdx.x;
  const int l = t & 63;
  const int w = t >> 6;
  const int bm = blockIdx.y * 128;
  const int bn = blockIdx.x * 128;
  const int wm = (w >> 1) * 64;
  const int wn = (w & 1) * 64;

  f32x4 acc[4][4];
#pragma unroll
  for (int i = 0; i < 4; ++i)
#pragma unroll
    for (int j = 0; j < 4; ++j)
#pragma unroll
      for (int r = 0; r < 4; ++r) acc[i][j][r] = 0.f;

  const int srow = w * 32 + (l >> 2);
  const int scol = (l & 3) * 8;
  const size_t gOffA = (size_t)(bm + srow) * K + scol;
  const size_t gOffW = (size_t)(bn + srow) * K + scol;
  const size_t rowStep = (size_t)16 * K;
  unsigned short* lAh0 = &AhS[(w * 32) * 32];
  unsigned short* lAh1 = &AhS[(w * 32 + 16) * 32];
  unsigned short* lAl0 = &AlS[(w * 32) * 32];
  unsigned short* lAl1 = &AlS[(w * 32 + 16) * 32];
  unsigned short* lWh0 = &WhS[(w * 32) * 32];
  unsigned short* lWh1 = &WhS[(w * 32 + 16) * 32];
  unsigned short* lWl0 = &WlS[(w * 32) * 32];
  unsigned short* lWl1 = &WlS[(w * 32 + 16) * 32];

  for (int k0 = 0; k0 < K; k0 += 32) {
    __syncthreads();
    __builtin_amdgcn_global_load_lds((const AS1 void*)(Ah + gOffA + k0),           (AS3 void*)lAh0, 16, 0, 0);
    __builtin_amdgcn_global_load_lds((const AS1 void*)(Ah + gOffA + rowStep + k0), (AS3 void*)lAh1, 16, 0, 0);
    __builtin_amdgcn_global_load_lds((const AS1 void*)(Al + gOffA + k0),           (AS3 void*)lAl0, 16, 0, 0);
    __builtin_amdgcn_global_load_lds((const AS1 void*)(Al + gOffA + rowStep + k0), (AS3 void*)lAl1, 16, 0, 0);
    __builtin_amdgcn_global_load_lds((const AS1 void*)(Wh + gOffW + k0),           (AS3 void*)lWh0, 16, 0, 0);
    __builtin_amdgcn_global_load_lds((const AS1 void*)(Wh + gOffW + rowStep + k0), (AS3 void*)lWh1, 16, 0, 0);
    __builtin_amdgcn_global_load_lds((const AS1 void*)(Wl + gOffW + k0),           (AS3 void*)lWl0, 16, 0, 0);
    __builtin_amdgcn_global_load_lds((const AS1 void*)(Wl + gOffW + rowStep + k0), (AS3 void*)lWl1, 16, 0, 0);
    __syncthreads();

    bf16x8 ah[4], al[4], bh[4], bl[4];
#pragma unroll
    for (int i = 0; i < 4; ++i) {
      int aoff = (wm + i * 16 + (l & 15)) * 32 + (l >> 4) * 8;
      int boff = (wn + i * 16 + (l & 15)) * 32 + (l >> 4) * 8;
      ah[i] = *(const bf16x8*)&AhS[aoff];
      al[i] = *(const bf16x8*)&AlS[aoff];
      bh[i] = *(const bf16x8*)&WhS[boff];
      bl[i] = *(const bf16x8*)&WlS[boff];
    }
#pragma unroll
    for (int i = 0; i < 4; ++i)
#pragma unroll
      for (int j = 0; j < 4; ++j) {
        acc[i][j] = __builtin_amdgcn_mfma_f32_16x16x32_bf16(ah[i], bh[j], acc[i][j], 0, 0, 0);
        acc[i][j] = __builtin_amdgcn_mfma_f32_16x16x32_bf16(ah[i], bl[j], acc[i][j], 0, 0, 0);
        acc[i][j] = __builtin_amdgcn_mfma_f32_16x16x32_bf16(al[i], bh[j], acc[i][j], 0, 0, 0);
      }
  }

  const int cr = (l >> 4) * 4;
  const int cc = l & 15;
#pragma unroll
  for (int i = 0; i < 4; ++i)
#pragma unroll
    for (int j = 0; j < 4; ++j)
#pragma unroll
      for (int r = 0; r < 4; ++r)
        C[(size_t)(bm + wm + i * 16 + cr + r) * N + (bn + wn + j * 16 + cc)] = acc[i][j][r];
}

// -------- merged q/k/v projection GEMM (one launch, routed by blockIdx.x) ----
__global__ __launch_bounds__(256) void gemm_qkv(const unsigned short* __restrict__ Ah,
                                                const unsigned short* __restrict__ Al,
                                                const unsigned short* __restrict__ wqh,
                                                const unsigned short* __restrict__ wql,
                                                const unsigned short* __restrict__ wkh,
                                                const unsigned short* __restrict__ wkl,
                                                const unsigned short* __restrict__ wvh,
                                                const unsigned short* __restrict__ wvl,
                                                float* __restrict__ q,
                                                float* __restrict__ kk,
                                                float* __restrict__ v) {
  const int K = 1024;
  const int bx = blockIdx.x;
  const unsigned short* Wh; const unsigned short* Wl; float* C; int N; int bn;
  if (bx < 8)       { Wh = wqh; Wl = wql; C = q;  N = 1024; bn = bx * 128; }
  else if (bx < 16) { Wh = wkh; Wl = wkl; C = kk; N = 1024; bn = (bx - 8) * 128; }
  else              { Wh = wvh; Wl = wvl; C = v;  N = 2048; bn = (bx - 16) * 128; }

  __shared__ unsigned short AhS[128 * 32];
  __shared__ unsigned short AlS[128 * 32];
  __shared__ unsigned short WhS[128 * 32];
  __shared__ unsigned short WlS[128 * 32];
  const int t = threadIdx.x;
  const int l = t & 63;
  const int w = t >> 6;
  const int bm = blockIdx.y * 128;
  const int wm = (w >> 1) * 64;
  const int wn = (w & 1) * 64;

  f32x4 acc[4][4];
#pragma unroll
  for (int i = 0; i < 4; ++i)
#pragma unroll
    for (int j = 0; j < 4; ++j)
#pragma unroll
      for (int r = 0; r < 4; ++r) acc[i][j][r] = 0.f;

  const int srow = w * 32 + (l >> 2);
  const int scol = (l & 3) * 8;
  const size_t gOffA = (size_t)(bm + srow) * K + scol;
  const size_t gOffW = (size_t)(bn + srow) * K + scol;
  const size_t rowStep = (size_t)16 * K;
  unsigned short* lAh0 = &AhS[(w * 32) * 32];
  unsigned short* lAh1 = &AhS[(w * 32 + 16) * 32];
  unsigned short* lAl0 = &AlS[(w * 32) * 32];
  unsigned short* lAl1 = &AlS[(w * 32 + 16) * 32];
  unsigned short* lWh0 = &WhS[(w * 32) * 32];
  unsigned short* lWh1 = &WhS[(w * 32 + 16) * 32];
  unsigned short* lWl0 = &WlS[(w * 32) * 32];
  unsigned short* lWl1 = &WlS[(w * 32 + 16) * 32];

  for (int k0 = 0; k0 < K; k0 += 32) {
    __syncthreads();
    __builtin_amdgcn_global_load_lds((const AS1 void*)(Ah + gOffA + k0),           (AS3 void*)lAh0, 16, 0, 0);
    __builtin_amdgcn_global_load_lds((const AS1 void*)(Ah + gOffA + rowStep + k0), (AS3 void*)lAh1, 16, 0, 0);
    __builtin_amdgcn_global_load_lds((const AS1 void*)(Al + gOffA + k0),           (AS3 void*)lAl0, 16, 0, 0);
    __builtin_amdgcn_global_load_lds((const AS1 void*)(Al + gOffA + rowStep + k0), (AS3 void*)lAl1, 16, 0, 0);
    __builtin_amdgcn_global_load_lds((const AS1 void*)(Wh + gOffW + k0),           (AS3 void*)lWh0, 16, 0, 0);
    __builtin_amdgcn_global_load_lds((const AS1 void*)(Wh + gOffW + rowStep + k0), (AS3 void*)lWh1, 16, 0, 0);
    __builtin_amdgcn_global_load_lds((const AS1 void*)(Wl + gOffW + k0),           (AS3 void*)lWl0, 16, 0, 0);
    __builtin_amdgcn_global_load_lds((const AS1 void*)(Wl + gOffW + rowStep + k0), (AS3 void*)lWl1, 16, 0, 0);
    __syncthreads();

    bf16x8 ah[4], al[4], bh[4], bl[4];
#pragma unroll
    for (int i = 0; i < 4; ++i) {
      int aoff = (wm + i * 16 + (l & 15)) * 32 + (l >> 4) * 8;
      int boff = (wn + i * 16 + (l & 15)) * 32 + (l >> 4) * 8;
      ah[i] = *(const bf16x8*)&AhS[aoff];
      al[i] = *(const bf16x8*)&AlS[aoff];
      bh[i] = *(const bf16x8*)&WhS[boff];
      bl[i] = *(const bf16x8*)&WlS[boff];
    }
#pragma unroll
    for (int i = 0; i < 4; ++i)
#pragma unroll
      for (int j = 0; j < 4; ++j) {
        acc[i][j] = __builtin_amdgcn_mfma_f32_16x16x32_bf16(ah[i], bh[j], acc[i][j], 0, 0, 0);
        acc[i][j] = __builtin_amdgcn_mfma_f32_16x16x32_bf16(ah[i], bl[j], acc[i][j], 0, 0, 0);
        acc[i][j] = __builtin_amdgcn_mfma_f32_16x16x32_bf16(al[i], bh[j], acc[i][j], 0, 0, 0);
      }
  }

  const int cr = (l >> 4) * 4;
  const int cc = l & 15;
#pragma unroll
  for (int i = 0; i < 4; ++i)
#pragma unroll
    for (int j = 0; j < 4; ++j)
#pragma unroll
      for (int r = 0; r < 4; ++r)
        C[(size_t)(bm + wm + i * 16 + cr + r) * N + (bn + wn + j * 16 + cc)] = acc[i][j][r];
}

// ---------------- RoPE (in-place on q and k), q also scaled by HK^-0.5 -------
__global__ __launch_bounds__(256) void rope_kernel(float* __restrict__ q,
                                                   float* __restrict__ k) {
  int idx = blockIdx.x * 256 + threadIdx.x;     // over B*T*H*128 = 4,194,304
  int f  = idx & 127;
  int h  = (idx >> 7) & 3;
  int tt = (idx >> 9) & 2047;
  int b  = idx >> 20;
  size_t a0 = ((size_t)(b * T_SEQ + tt)) * KDIM + h * HK + f;
  size_t a1 = a0 + 128;
  float invf = powf(10000.0f, -(float)f * (1.0f / 128.0f));
  float ang  = (float)tt * invf;
  float s, c;
  sincosf(ang, &s, &c);
  float q1 = q[a0], q2 = q[a1];
  q[a0] = (q1 * c - q2 * s) * 0.0625f;
  q[a1] = (q2 * c + q1 * s) * 0.0625f;
  float k1 = k[a0], k2 = k[a1];
  k[a0] = k1 * c - k2 * s;
  k[a1] = k2 * c + k1 * s;
}

// ---------------- Retention pass 1: intra-chunk (fully parallel) -------------
__global__ __launch_bounds__(256) void retn_intra(const float* __restrict__ q,
                                                  const float* __restrict__ k,
                                                  const float* __restrict__ v,
                                                  float* __restrict__ o) {
  const int n = blockIdx.x, h = blockIdx.y, b = blockIdx.z;
  const int t = threadIdx.x;
  const int t0 = n * 64;
  __shared__ float gpow[65];
  __shared__ __align__(16) float qS[64][68];
  __shared__ __align__(16) float kS[64][68];
  __shared__ __align__(16) float attnS[64][68];
  if (t <= 64) {
    float gamma = 1.0f - exp2f(-5.0f - (float)h);
    gpow[t] = powf(gamma, (float)t);
  }
  const size_t baseQK = (size_t)(b * T_SEQ + t0) * KDIM + h * HK;
  const size_t baseV  = (size_t)(b * T_SEQ + t0) * VDIM + h * HV;
  const int i0 = (t >> 4) * 4;
  const int j0 = (t & 15) * 4;
  float acc[4][4] = {};
  for (int s = 0; s < 4; ++s) {              // dk slices of 64
    __syncthreads();
    __builtin_amdgcn_sched_barrier(0);
#pragma unroll
    for (int r = 0; r < 4; ++r) {            // stage 64x64 as float4
      int idx = t + 256 * r;
      int row = idx >> 4, c4 = (idx & 15) * 4;
      *(float4*)&qS[row][c4] = *(const float4*)&q[baseQK + (size_t)row * KDIM + s * 64 + c4];
      *(float4*)&kS[row][c4] = *(const float4*)&k[baseQK + (size_t)row * KDIM + s * 64 + c4];
    }
    __syncthreads();
    __builtin_amdgcn_sched_barrier(0);
    for (int d = 0; d < 64; d += 4) {
      float4 a0 = *(const float4*)&qS[i0 + 0][d];
      float4 a1 = *(const float4*)&qS[i0 + 1][d];
      float4 a2 = *(const float4*)&qS[i0 + 2][d];
      float4 a3 = *(const float4*)&qS[i0 + 3][d];
      float4 b0 = *(const float4*)&kS[j0 + 0][d];
      float4 b1 = *(const float4*)&kS[j0 + 1][d];
      float4 b2 = *(const float4*)&kS[j0 + 2][d];
      float4 b3 = *(const float4*)&kS[j0 + 3][d];
      acc[0][0]=fmaf(a0.x,b0.x,acc[0][0]); acc[0][0]=fmaf(a0.y,b0.y,acc[0][0]); acc[0][0]=fmaf(a0.z,b0.z,acc[0][0]); acc[0][0]=fmaf(a0.w,b0.w,acc[0][0]);
      acc[0][1]=fmaf(a0.x,b1.x,acc[0][1]); acc[0][1]=fmaf(a0.y,b1.y,acc[0][1]); acc[0][1]=fmaf(a0.z,b1.z,acc[0][1]); acc[0][1]=fmaf(a0.w,b1.w,acc[0][1]);
      acc[0][2]=fmaf(a0.x,b2.x,acc[0][2]); acc[0][2]=fmaf(a0.y,b2.y,acc[0][2]); acc[0][2]=fmaf(a0.z,b2.z,acc[0][2]); acc[0][2]=fmaf(a0.w,b2.w,acc[0][2]);
      acc[0][3]=fmaf(a0.x,b3.x,acc[0][3]); acc[0][3]=fmaf(a0.y,b3.y,acc[0][3]); acc[0][3]=fmaf(a0.z,b3.z,acc[0][3]); acc[0][3]=fmaf(a0.w,b3.w,acc[0][3]);
      acc[1][0]=fmaf(a1.x,b0.x,acc[1][0]); acc[1][0]=fmaf(a1.y,b0.y,acc[1][0]); acc[1][0]=fmaf(a1.z,b0.z,acc[1][0]); acc[1][0]=fmaf(a1.w,b0.w,acc[1][0]);
      acc[1][1]=fmaf(a1.x,b1.x,acc[1][1]); acc[1][1]=fmaf(a1.y,b1.y,acc[1][1]); acc[1][1]=fmaf(a1.z,b1.z,acc[1][1]); acc[1][1]=fmaf(a1.w,b1.w,acc[1][1]);
      acc[1][2]=fmaf(a1.x,b2.x,acc[1][2]); acc[1][2]=fmaf(a1.y,b2.y,acc[1][2]); acc[1][2]=fmaf(a1.z,b2.z,acc[1][2]); acc[1][2]=fmaf(a1.w,b2.w,acc[1][2]);
      acc[1][3]=fmaf(a1.x,b3.x,acc[1][3]); acc[1][3]=fmaf(a1.y,b3.y,acc[1][3]); acc[1][3]=fmaf(a1.z,b3.z,acc[1][3]); acc[1][3]=fmaf(a1.w,b3.w,acc[1][3]);
      acc[2][0]=fmaf(a2.x,b0.x,acc[2][0]); acc[2][0]=fmaf(a2.y,b0.y,acc[2][0]); acc[2][0]=fmaf(a2.z,b0.z,acc[2][0]); acc[2][0]=fmaf(a2.w,b0.w,acc[2][0]);
      acc[2][1]=fmaf(a2.x,b1.x,acc[2][1]); acc[2][1]=fmaf(a2.y,b1.y,acc[2][1]); acc[2][1]=fmaf(a2.z,b1.z,acc[2][1]); acc[2][1]=fmaf(a2.w,b1.w,acc[2][1]);
      acc[2][2]=fmaf(a2.x,b2.x,acc[2][2]); acc[2][2]=fmaf(a2.y,b2.y,acc[2][2]); acc[2][2]=fmaf(a2.z,b2.z,acc[2][2]); acc[2][2]=fmaf(a2.w,b2.w,acc[2][2]);
      acc[2][3]=fmaf(a2.x,b3.x,acc[2][3]); acc[2][3]=fmaf(a2.y,b3.y,acc[2][3]); acc[2][3]=fmaf(a2.z,b3.z,acc[2][3]); acc[2][3]=fmaf(a2.w,b3.w,acc[2][3]);
      acc[3][0]=fmaf(a3.x,b0.x,acc[3][0]); acc[3][0]=fmaf(a3.y,b0.y,acc[3][0]); acc[3][0]=fmaf(a3.z,b0.z,acc[3][0]); acc[3][0]=fmaf(a3.w,b0.w,acc[3][0]);
      acc[3][1]=fmaf(a3.x,b1.x,acc[3][1]); acc[3][1]=fmaf(a3.y,b1.y,acc[3][1]); acc[3][1]=fmaf(a3.z,b1.z,acc[3][1]); acc[3][1]=fmaf(a3.w,b1.w,acc[3][1]);
      acc[3][2]=fmaf(a3.x,b2.x,acc[3][2]); acc[3][2]=fmaf(a3.y,b2.y,acc[3][2]); acc[3][2]=fmaf(a3.z,b2.z,acc[3][2]); acc[3][2]=fmaf(a3.w,b2.w,acc[3][2]);
      acc[3][3]=fmaf(a3.x,b3.x,acc[3][3]); acc[3][3]=fmaf(a3.y,b3.y,acc[3][3]); acc[3][3]=fmaf(a3.z,b3.z,acc[3][3]); acc[3][3]=fmaf(a3.w,b3.w,acc[3][3]);
    }
  }
  __syncthreads();
#pragma unroll
  for (int ii = 0; ii < 4; ++ii)
#pragma unroll
    for (int jj = 0; jj < 4; ++jj) {
      int i = i0 + ii, j = j0 + jj;
      attnS[i][j] = (i >= j) ? acc[ii][jj] * gpow[i - j] : 0.0f;
    }
  float (*vS)[68] = qS;
  for (int vb = 0; vb < 8; ++vb) {
    __syncthreads();
    __builtin_amdgcn_sched_barrier(0);
#pragma unroll
    for (int r = 0; r < 4; ++r) {
      int idx = t + 256 * r;
      int row = idx >> 4, c4 = (idx & 15) * 4;
      *(float4*)&vS[row][c4] = *(const float4*)&v[baseV + (size_t)row * VDIM + vb * 64 + c4];
    }
    __syncthreads();
    __builtin_amdgcn_sched_barrier(0);
    float oa[4][4] = {};
    for (int j = 0; j < 64; j += 4) {
      float4 p0 = *(const float4*)&attnS[i0 + 0][j];
      float4 p1 = *(const float4*)&attnS[i0 + 1][j];
      float4 p2 = *(const float4*)&attnS[i0 + 2][j];
      float4 p3 = *(const float4*)&attnS[i0 + 3][j];
      float4 v0 = *(const float4*)&vS[j + 0][j0];
      float4 v1 = *(const float4*)&vS[j + 1][j0];
      float4 v2 = *(const float4*)&vS[j + 2][j0];
      float4 v3 = *(const float4*)&vS[j + 3][j0];
      oa[0][0]=fmaf(p0.x,v0.x,oa[0][0]); oa[0][0]=fmaf(p0.y,v1.x,oa[0][0]); oa[0][0]=fmaf(p0.z,v2.x,oa[0][0]); oa[0][0]=fmaf(p0.w,v3.x,oa[0][0]);
      oa[0][1]=fmaf(p0.x,v0.y,oa[0][1]); oa[0][1]=fmaf(p0.y,v1.y,oa[0][1]); oa[0][1]=fmaf(p0.z,v2.y,oa[0][1]); oa[0][1]=fmaf(p0.w,v3.y,oa[0][1]);
      oa[0][2]=fmaf(p0.x,v0.z,oa[0][2]); oa[0][2]=fmaf(p0.y,v1.z,oa[0][2]); oa[0][2]=fmaf(p0.z,v2.z,oa[0][2]); oa[0][2]=fmaf(p0.w,v3.z,oa[0][2]);
      oa[0][3]=fmaf(p0.x,v0.w,oa[0][3]); oa[0][3]=fmaf(p0.y,v1.w,oa[0][3]); oa[0][3]=fmaf(p0.z,v2.w,oa[0][3]); oa[0][3]=fmaf(p0.w,v3.w,oa[0][3]);
      oa[1][0]=fmaf(p1.x,v0.x,oa[1][0]); oa[1][0]=fmaf(p1.y,v1.x,oa[1][0]); oa[1][0]=fmaf(p1.z,v2.x,oa[1][0]); oa[1][0]=fmaf(p1.w,v3.x,oa[1][0]);
      oa[1][1]=fmaf(p1.x,v0.y,oa[1][1]); oa[1][1]=fmaf(p1.y,v1.y,oa[1][1]); oa[1][1]=fmaf(p1.z,v2.y,oa[1][1]); oa[1][1]=fmaf(p1.w,v3.y,oa[1][1]);
      oa[1][2]=fmaf(p1.x,v0.z,oa[1][2]); oa[1][2]=fmaf(p1.y,v1.z,oa[1][2]); oa[1][2]=fmaf(p1.z,v2.z,oa[1][2]); oa[1][2]=fmaf(p1.w,v3.z,oa[1][2]);
      oa[1][3]=fmaf(p1.x,v0.w,oa[1][3]); oa[1][3]=fmaf(p1.y,v1.w,oa[1][3]); oa[1][3]=fmaf(p1.z,v2.w,oa[1][3]); oa[1][3]=fmaf(p1.w,v3.w,oa[1][3]);
      oa[2][0]=fmaf(p2.x,v0.x,oa[2][0]); oa[2][0]=fmaf(p2.y,v1.x,oa[2][0]); oa[2][0]=fmaf(p2.z,v2.x,oa[2][0]); oa[2][0]=fmaf(p2.w,v3.x,oa[2][0]);
      oa[2][1]=fmaf(p2.x,v0.y,oa[2][1]); oa[2][1]=fmaf(p2.y,v1.y,oa[2][1]); oa[2][1]=fmaf(p2.z,v2.y,oa[2][1]); oa[2][1]=fmaf(p2.w,v3.y,oa[2][1]);
      oa[2][2]=fmaf(p2.x,v0.z,oa[2][2]); oa[2][2]=fmaf(p2.y,v1.z,oa[2][2]); oa[2][2]=fmaf(p2.z,v2.z,oa[2][2]); oa[2][2]=fmaf(p2.w,v3.z,oa[2][2]);
      oa[2][3]=fmaf(p2.x,v0.w,oa[2][3]); oa[2][3]=fmaf(p2.y,v1.w,oa[2][3]); oa[2][3]=fmaf(p2.z,v2.w,oa[2][3]); oa[2][3]=fmaf(p2.w,v3.w,oa[2][3]);
      oa[3][0]=fmaf(p3.x,v0.x,oa[3][0]); oa[3][0]=fmaf(p3.y,v1.x,oa[3][0]); oa[3][0]=fmaf(p3.z,v2.x,oa[3][0]); oa[3][0]=fmaf(p3.w,v3.x,oa[3][0]);
      oa[3][1]=fmaf(p3.x,v0.y,oa[3][1]); oa[3][1]=fmaf(p3.y,v1.y,oa[3][1]); oa[3][1]=fmaf(p3.z,v2.y,oa[3][1]); oa[3][1]=fmaf(p3.w,v3.y,oa[3][1]);
      oa[3][2]=fmaf(p3.x,v0.z,oa[3][2]); oa[3][2]=fmaf(p3.y,v1.z,oa[3][2]); oa[3][2]=fmaf(p3.z,v2.z,oa[3][2]); oa[3][2]=fmaf(p3.w,v3.z,oa[3][2]);
      oa[3][3]=fmaf(p3.x,v0.w,oa[3][3]); oa[3][3]=fmaf(p3.y,v1.w,oa[3][3]); oa[3][3]=fmaf(p3.z,v2.w,oa[3][3]); oa[3][3]=fmaf(p3.w,v3.w,oa[3][3]);
    }
#pragma unroll
    for (int ii = 0; ii < 4; ++ii)
      *(float4*)&o[baseV + (size_t)(i0 + ii) * VDIM + vb * 64 + j0] =
          make_float4(oa[ii][0], oa[ii][1], oa[ii][2], oa[ii][3]);
  }
}

// =================== Retention inter-chunk: two-level scan ===================
// ROUND-7 POST-MORTEM: gstate was the largest improvable kernel (~110us by the
// LDS-issue model: 24 waves/CU x 1088 b128 x ~12cyc). ROUND-8: retile gstate
// 64x64 -> 128x128 per WG (grid z 32->8). Each thread owns S[2][2][4][4] = 64
// regs as two 4-wide halves at column offsets {0,+64}, so LDS read addresses
// keep the proven step-4 (2-way, free) bank pattern. Per-work LDS issue
// exactly halves (6 waves/CU x 2176). Same anti-spill skeleton as the
// 112-VGPR retn_inter2. Per-element FP accumulation order unchanged.

// ---- pass A: group-local state sums (128x128 tiles) -----------------------
__global__ __launch_bounds__(256) void retn_gstate(const float* __restrict__ k,
                                                   const float* __restrict__ v,
                                                   float* __restrict__ Tbuf) {
  // grid (16, 3, 8): x = b*4+h, y = g (0..2), z: dkt = z>>2 (0..1), dvt = z&3
  const int bh = blockIdx.x; const int b = bh >> 2, h = bh & 3;
  const int g = blockIdx.y;
  const int dkt = blockIdx.z >> 2, dvt = blockIdx.z & 3;
  const int t = threadIdx.x;
  __shared__ float gpow[65];
  __shared__ __align__(16) float kS[64][132];
  __shared__ __align__(16) float vS[64][132];
  if (t <= 64) gpow[t] = powf(1.0f - exp2f(-5.0f - (float)h), (float)t);
  __syncthreads();
  const float gC = gpow[64];
  const size_t baseK = (size_t)(b * T_SEQ + g * 512) * KDIM + h * HK + dkt * 128;
  const size_t baseV = (size_t)(b * T_SEQ + g * 512) * VDIM + h * HV + dvt * 128;
  const int dk0 = (t & 15) * 4;   // dk rows: dk0..+3 and dk0+64..+67
  const int c0  = (t >> 4) * 4;   // dv cols: c0..+3  and c0+64..+67
  // S: 64 regs, compile-time indices only, never address-taken.
  float S[2][2][4][4] = {};       // [dk-half][dv-half][dk-sub][dv-sub]
  for (int c = 0; c < 8; ++c) {
    const int t0 = c * 64;
    __syncthreads();
    __builtin_amdgcn_sched_barrier(0);
#pragma unroll
    for (int r = 0; r < 8; ++r) {           // stage 64x128 k~ and v as float4
      int idx = t + 256 * r; int row = idx >> 5, c4 = (idx & 31) * 4;
      float4 kv = *(const float4*)&k[baseK + (size_t)(t0 + row) * KDIM + c4];
      float kd = gpow[63 - row];
      kv.x *= kd; kv.y *= kd; kv.z *= kd; kv.w *= kd;
      *(float4*)&kS[row][c4] = kv;
      *(float4*)&vS[row][c4] = *(const float4*)&v[baseV + (size_t)(t0 + row) * VDIM + c4];
    }
    __syncthreads();
    __builtin_amdgcn_sched_barrier(0);
#pragma unroll
    for (int p = 0; p < 2; ++p)
#pragma unroll
      for (int qh = 0; qh < 2; ++qh)
#pragma unroll
        for (int ii = 0; ii < 4; ++ii)
#pragma unroll
          for (int jj = 0; jj < 4; ++jj) S[p][qh][ii][jj] *= gC;
    for (int j = 0; j < 64; ++j) {
      float4 ka = *(const float4*)&kS[j][dk0];
      float4 kb = *(const float4*)&kS[j][dk0 + 64];
      float4 va = *(const float4*)&vS[j][c0];
      float4 vb = *(const float4*)&vS[j][c0 + 64];
      float kr[8] = {ka.x, ka.y, ka.z, ka.w, kb.x, kb.y, kb.z, kb.w};
      float vr[8] = {va.x, va.y, va.z, va.w, vb.x, vb.y, vb.z, vb.w};
#pragma unroll
      for (int ii = 0; ii < 8; ++ii)
#pragma unroll
        for (int jj = 0; jj < 8; ++jj)
          S[ii >> 2][jj >> 2][ii & 3][jj & 3] =
              fmaf(kr[ii], vr[jj], S[ii >> 2][jj >> 2][ii & 3][jj & 3]);
    }
  }
  const size_t tbRow = ((size_t)g * 16 + bh) * 256 + dkt * 128 + dk0;
  const size_t tbCol = (size_t)dvt * 128 + c0;
#pragma unroll
  for (int p = 0; p < 2; ++p)
#pragma unroll
    for (int ii = 0; ii < 4; ++ii) {
      size_t rowb = (tbRow + p * 64 + ii) * 512 + tbCol;
      *(float4*)&Tbuf[rowb]      = make_float4(S[p][0][ii][0], S[p][0][ii][1], S[p][0][ii][2], S[p][0][ii][3]);
      *(float4*)&Tbuf[rowb + 64] = make_float4(S[p][1][ii][0], S[p][1][ii][1], S[p][1][ii][2], S[p][1][ii][3]);
    }
}

// ---- pass B: exclusive scan over the 4 groups (in-place) ------------------
__global__ __launch_bounds__(256) void retn_scan(float* __restrict__ Tbuf) {
  int i = blockIdx.x * 256 + threadIdx.x;   // float4 index within one g-slab
  int h = (i >> 15) & 3;                    // (i*4)>>17 & 3
  float gamma = 1.0f - exp2f(-5.0f - (float)h);
  float gG = powf(gamma, 512.0f);           // gC^8 = gamma^(64*8)
  float4* T = (float4*)Tbuf;
  const int slab = 524288;                  // 16*256*512/4
  float4 t0 = T[i], t1 = T[i + slab], t2 = T[i + 2 * slab];
  float4 s2, s3;
  s2.x = fmaf(gG, t0.x, t1.x); s2.y = fmaf(gG, t0.y, t1.y);
  s2.z = fmaf(gG, t0.z, t1.z); s2.w = fmaf(gG, t0.w, t1.w);
  s3.x = fmaf(gG, s2.x, t2.x); s3.y = fmaf(gG, s2.y, t2.y);
  s3.z = fmaf(gG, s2.z, t2.z); s3.w = fmaf(gG, s2.w, t2.w);
  T[i + slab] = s2; T[i + 2 * slab] = s3;
}

// ---- pass C: inter-chunk output, full-dk state in regs, no atomics --------
__global__ __launch_bounds__(256) void retn_inter2(const float* __restrict__ q,
                                                   const float* __restrict__ k,
                                                   const float* __restrict__ v,
                                                   float* __restrict__ o,
                                                   const float* __restrict__ Sbuf) {
  // grid (16, 4, 8): x = b*4+h, y = g, z = dvt (64-wide dv tiles)
  const int bh = blockIdx.x; const int b = bh >> 2, h = bh & 3;
  const int g = blockIdx.y;
  const int dvt = blockIdx.z;
  const int t = threadIdx.x;
  __shared__ float gpow[65];
  __shared__ __align__(16) float qS[64][68];  // q~ block (64x64)
  __shared__ __align__(16) float kS[64][68];  // k~ block (64x64)
  __shared__ __align__(16) float sS[64][68];  // state-block publish (64x64)
  __shared__ __align__(16) float vS[64][68];  // v chunk (64x64)
  if (t <= 64) gpow[t] = powf(1.0f - exp2f(-5.0f - (float)h), (float)t);
  __syncthreads();
  const float gC = gpow[64];
  const int rq = (t & 15) * 4;   // state rows within a dk-block (publish/j-loop)
  const int c0 = (t >> 4) * 4;   // state cols (0,4,..,60)
  const int i0 = (t >> 4) * 4;   // o-tile rows
  const int v0 = (t & 15) * 4;   // o-tile cols
  const size_t baseQK = (size_t)(b * T_SEQ + g * 512) * KDIM + h * HK;
  const size_t baseV  = (size_t)(b * T_SEQ + g * 512) * VDIM + h * HV + (size_t)dvt * 64;

  // S: 64 regs/thread, compile-time indices only, never address-taken.
  float S[4][4][4];              // [dk-block][row][col]; cols c0..c0+3
  if (g > 0) {
    const size_t sb = (((size_t)(g - 1) * 16 + bh) * 256) * 512 + (size_t)dvt * 64 + c0;
#pragma unroll
    for (int b4 = 0; b4 < 4; ++b4)
#pragma unroll
      for (int i = 0; i < 4; ++i) {
        float4 tmp = *(const float4*)&Sbuf[sb + (size_t)(b4 * 64 + rq + i) * 512];
        S[b4][i][0] = tmp.x; S[b4][i][1] = tmp.y; S[b4][i][2] = tmp.z; S[b4][i][3] = tmp.w;
      }
  } else {
#pragma unroll
    for (int b4 = 0; b4 < 4; ++b4)
#pragma unroll
      for (int i = 0; i < 4; ++i) {
        S[b4][i][0] = 0.f; S[b4][i][1] = 0.f; S[b4][i][2] = 0.f; S[b4][i][3] = 0.f;
      }
  }

  for (int c = 0; c < 8; ++c) {
    const int t0 = c * 64;
    const bool doO = (g > 0 || c > 0);     // block-uniform; S==0 otherwise
    __syncthreads();                       // prev chunk's vS readers done
    __builtin_amdgcn_sched_barrier(0);
#pragma unroll
    for (int r = 0; r < 4; ++r) {          // stage v chunk 64x64
      int idx = t + 256 * r; int row = idx >> 4, c4 = (idx & 15) * 4;
      *(float4*)&vS[row][c4] = *(const float4*)&v[baseV + (size_t)(t0 + row) * VDIM + c4];
    }
    float oa[4][4] = {};
#pragma unroll
    for (int b4 = 0; b4 < 4; ++b4) {
      __syncthreads();                     // prev b4's qS/kS/sS readers done (covers vS write at b4=0)
      __builtin_amdgcn_sched_barrier(0);
      if (doO) {
        // publish this dk-block of S (OLD state) for the o-phase
#pragma unroll
        for (int i = 0; i < 4; ++i)
          *(float4*)&sS[rq + i][c0] =
              make_float4(S[b4][i][0], S[b4][i][1], S[b4][i][2], S[b4][i][3]);
        // stage q~ block (64x64), scaled by cross_dec
#pragma unroll
        for (int r = 0; r < 4; ++r) {
          int idx = t + 256 * r; int row = idx >> 4, c4 = (idx & 15) * 4;
          float4 qv = *(const float4*)&q[baseQK + (size_t)(t0 + row) * KDIM + b4 * 64 + c4];
          float gp = gpow[row + 1];
          qv.x *= gp; qv.y *= gp; qv.z *= gp; qv.w *= gp;
          *(float4*)&qS[row][c4] = qv;
        }
      }
      // stage k~ block (64x64), scaled by k_dec
#pragma unroll
      for (int r = 0; r < 4; ++r) {
        int idx = t + 256 * r; int row = idx >> 4, c4 = (idx & 15) * 4;
        float4 kv = *(const float4*)&k[baseQK + (size_t)(t0 + row) * KDIM + b4 * 64 + c4];
        float kd = gpow[63 - row];
        kv.x *= kd; kv.y *= kd; kv.z *= kd; kv.w *= kd;
        *(float4*)&kS[row][c4] = kv;
      }
      __syncthreads();
      __builtin_amdgcn_sched_barrier(0);
      if (doO) {
        // o-phase: oa += q~S(64x64) @ sS(64x64), this thread: 4 rows x 4 cols
        for (int d = 0; d < 64; d += 4) {
          float4 a0 = *(const float4*)&qS[i0 + 0][d];
          float4 a1 = *(const float4*)&qS[i0 + 1][d];
          float4 a2 = *(const float4*)&qS[i0 + 2][d];
          float4 a3 = *(const float4*)&qS[i0 + 3][d];
          float4 s0 = *(const float4*)&sS[d + 0][v0];
          float4 s1 = *(const float4*)&sS[d + 1][v0];
          float4 s2 = *(const float4*)&sS[d + 2][v0];
          float4 s3 = *(const float4*)&sS[d + 3][v0];
          oa[0][0]=fmaf(a0.x,s0.x,oa[0][0]); oa[0][0]=fmaf(a0.y,s1.x,oa[0][0]); oa[0][0]=fmaf(a0.z,s2.x,oa[0][0]); oa[0][0]=fmaf(a0.w,s3.x,oa[0][0]);
          oa[0][1]=fmaf(a0.x,s0.y,oa[0][1]); oa[0][1]=fmaf(a0.y,s1.y,oa[0][1]); oa[0][1]=fmaf(a0.z,s2.y,oa[0][1]); oa[0][1]=fmaf(a0.w,s3.y,oa[0][1]);
          oa[0][2]=fmaf(a0.x,s0.z,oa[0][2]); oa[0][2]=fmaf(a0.y,s1.z,oa[0][2]); oa[0][2]=fmaf(a0.z,s2.z,oa[0][2]); oa[0][2]=fmaf(a0.w,s3.z,oa[0][2]);
          oa[0][3]=fmaf(a0.x,s0.w,oa[0][3]); oa[0][3]=fmaf(a0.y,s1.w,oa[0][3]); oa[0][3]=fmaf(a0.z,s2.w,oa[0][3]); oa[0][3]=fmaf(a0.w,s3.w,oa[0][3]);
          oa[1][0]=fmaf(a1.x,s0.x,oa[1][0]); oa[1][0]=fmaf(a1.y,s1.x,oa[1][0]); oa[1][0]=fmaf(a1.z,s2.x,oa[1][0]); oa[1][0]=fmaf(a1.w,s3.x,oa[1][0]);
          oa[1][1]=fmaf(a1.x,s0.y,oa[1][1]); oa[1][1]=fmaf(a1.y,s1.y,oa[1][1]); oa[1][1]=fmaf(a1.z,s2.y,oa[1][1]); oa[1][1]=fmaf(a1.w,s3.y,oa[1][1]);
          oa[1][2]=fmaf(a1.x,s0.z,oa[1][2]); oa[1][2]=fmaf(a1.y,s1.z,oa[1][2]); oa[1][2]=fmaf(a1.z,s2.z,oa[1][2]); oa[1][2]=fmaf(a1.w,s3.z,oa[1][2]);
          oa[1][3]=fmaf(a1.x,s0.w,oa[1][3]); oa[1][3]=fmaf(a1.y,s1.w,oa[1][3]); oa[1][3]=fmaf(a1.z,s2.w,oa[1][3]); oa[1][3]=fmaf(a1.w,s3.w,oa[1][3]);
          oa[2][0]=fmaf(a2.x,s0.x,oa[2][0]); oa[2][0]=fmaf(a2.y,s1.x,oa[2][0]); oa[2][0]=fmaf(a2.z,s2.x,oa[2][0]); oa[2][0]=fmaf(a2.w,s3.x,oa[2][0]);
          oa[2][1]=fmaf(a2.x,s0.y,oa[2][1]); oa[2][1]=fmaf(a2.y,s1.y,oa[2][1]); oa[2][1]=fmaf(a2.z,s2.y,oa[2][1]); oa[2][1]=fmaf(a2.w,s3.y,oa[2][1]);
          oa[2][2]=fmaf(a2.x,s0.z,oa[2][2]); oa[2][2]=fmaf(a2.y,s1.z,oa[2][2]); oa[2][2]=fmaf(a2.z,s2.z,oa[2][2]); oa[2][2]=fmaf(a2.w,s3.z,oa[2][2]);
          oa[2][3]=fmaf(a2.x,s0.w,oa[2][3]); oa[2][3]=fmaf(a2.y,s1.w,oa[2][3]); oa[2][3]=fmaf(a2.z,s2.w,oa[2][3]); oa[2][3]=fmaf(a2.w,s3.w,oa[2][3]);
          oa[3][0]=fmaf(a3.x,s0.x,oa[3][0]); oa[3][0]=fmaf(a3.y,s1.x,oa[3][0]); oa[3][0]=fmaf(a3.z,s2.x,oa[3][0]); oa[3][0]=fmaf(a3.w,s3.x,oa[3][0]);
          oa[3][1]=fmaf(a3.x,s0.y,oa[3][1]); oa[3][1]=fmaf(a3.y,s1.y,oa[3][1]); oa[3][1]=fmaf(a3.z,s2.y,oa[3][1]); oa[3][1]=fmaf(a3.w,s3.y,oa[3][1]);
          oa[3][2]=fmaf(a3.x,s0.z,oa[3][2]); oa[3][2]=fmaf(a3.y,s1.z,oa[3][2]); oa[3][2]=fmaf(a3.z,s2.z,oa[3][2]); oa[3][2]=fmaf(a3.w,s3.z,oa[3][2]);
          oa[3][3]=fmaf(a3.x,s0.w,oa[3][3]); oa[3][3]=fmaf(a3.y,s1.w,oa[3][3]); oa[3][3]=fmaf(a3.z,s2.w,oa[3][3]); oa[3][3]=fmaf(a3.w,s3.w,oa[3][3]);
        }
      }
      // update: S[b4] = gC*S[b4] + k~^T v (rows rq..rq+3, cols c0..c0+3)
#pragma unroll
      for (int ii = 0; ii < 4; ++ii) {
        S[b4][ii][0] *= gC; S[b4][ii][1] *= gC; S[b4][ii][2] *= gC; S[b4][ii][3] *= gC;
      }
      for (int j = 0; j < 64; ++j) {
        float4 kv = *(const float4*)&kS[j][rq];
        float4 vv = *(const float4*)&vS[j][c0];
        S[b4][0][0] = fmaf(kv.x, vv.x, S[b4][0][0]); S[b4][0][1] = fmaf(kv.x, vv.y, S[b4][0][1]);
        S[b4][0][2] = fmaf(kv.x, vv.z, S[b4][0][2]); S[b4][0][3] = fmaf(kv.x, vv.w, S[b4][0][3]);
        S[b4][1][0] = fmaf(kv.y, vv.x, S[b4][1][0]); S[b4][1][1] = fmaf(kv.y, vv.y, S[b4][1][1]);
        S[b4][1][2] = fmaf(kv.y, vv.z, S[b4][1][2]); S[b4][1][3] = fmaf(kv.y, vv.w, S[b4][1][3]);
        S[b4][2][0] = fmaf(kv.z, vv.x, S[b4][2][0]); S[b4][2][1] = fmaf(kv.z, vv.y, S[b4][2][1]);
        S[b4][2][2] = fmaf(kv.z, vv.z, S[b4][2][2]); S[b4][2][3] = fmaf(kv.z, vv.w, S[b4][2][3]);
        S[b4][3][0] = fmaf(kv.w, vv.x, S[b4][3][0]); S[b4][3][1] = fmaf(kv.w, vv.y, S[b4][3][1]);
        S[b4][3][2] = fmaf(kv.w, vv.z, S[b4][3][2]); S[b4][3][3] = fmaf(kv.w, vv.w, S[b4][3][3]);
      }
    }
    // o += oa (skipped when S was all-zero: oa == 0)
    if (doO) {
#pragma unroll
      for (int ii = 0; ii < 4; ++ii) {
        size_t addr = baseV + (size_t)(t0 + i0 + ii) * VDIM + v0;
        float4 ov = *(const float4*)&o[addr];
        ov.x += oa[ii][0]; ov.y += oa[ii][1]; ov.z += oa[ii][2]; ov.w += oa[ii][3];
        *(float4*)&o[addr] = ov;
      }
    }
  }
}

// ------- RMS group-norm + SiLU(g) gate + bf16 hi/lo split (fused) ------------
__global__ __launch_bounds__(256) void norm_gate_cast(const float* __restrict__ o,
                                                      const float* __restrict__ g,
                                                      const float* __restrict__ gnw,
                                                      unsigned short* __restrict__ oh,
                                                      unsigned short* __restrict__ ol) {
  const int row = blockIdx.x;
  const size_t base = (size_t)row * 512;
  const int t = threadIdx.x;
  float x0 = o[base + t], x1 = o[base + t + 256];
  float ss = x0 * x0 + x1 * x1;
#pragma unroll
  for (int off = 32; off > 0; off >>= 1) ss += __shfl_down(ss, off, 64);
  __shared__ float wsum[4];
  if ((t & 63) == 0) wsum[t >> 6] = ss;
  __syncthreads();
  float tot = wsum[0] + wsum[1] + wsum[2] + wsum[3];
  float scale = rsqrtf(tot * (1.0f / 512.0f) + 1e-5f);
  float g0 = g[base + t], g1 = g[base + t + 256];
  float r0 = x0 * scale * gnw[t]       * (g0 / (1.0f + expf(-g0)));
  float r1 = x1 * scale * gnw[t + 256] * (g1 / (1.0f + expf(-g1)));
  unsigned short h0 = f2bf(r0);
  unsigned short h1 = f2bf(r1);
  oh[base + t]       = h0; ol[base + t]       = f2bf(r0 - bf2f(h0));
  oh[base + t + 256] = h1; ol[base + t + 256] = f2bf(r1 - bf2f(h1));
}

extern "C" void kernel_launch(void* const* d_in, const int* in_sizes, int n_in,
                              void* d_out, int out_size, void* d_ws, size_t ws_size,
                              hipStream_t stream) {
  const float* x   = (const float*)d_in[0];
  const float* Wq  = (const float*)d_in[1];
  const float* Wk  = (const float*)d_in[2];
  const float* Wv  = (const float*)d_in[3];
  const float* Wg  = (const float*)d_in[4];
  const float* Wo  = (const float*)d_in[5];
  const float* gnw = (const float*)d_in[6];
  float* out = (float*)d_out;

  // workspace = 256 MiB exactly:
  // [q 32][k 32][v 64][o 64][x-splits 32][W-splits 32]
  // o-splits (64) alias dead v; g (64) aliases dead q+k.
  // d_out (32 MiB) doubles as group-state scratch (24 MiB) until final GEMM.
  const size_t M8 = (size_t)8192;
  float* q  = (float*)d_ws;
  float* kk = q  + M8 * 1024;
  float* v  = kk + M8 * 1024;
  float* o  = v  + M8 * 2048;
  unsigned short* xh  = (unsigned short*)(o + M8 * 2048);
  unsigned short* xl  = xh  + M8 * 1024;
  unsigned short* wqh = xl  + M8 * 1024;
  unsigned short* wql = wqh + (size_t)1024 * 1024;
  unsigned short* wkh = wql + (size_t)1024 * 1024;
  unsigned short* wkl = wkh + (size_t)1024 * 1024;
  unsigned short* wvh = wkl + (size_t)1024 * 1024;
  unsigned short* wvl = wvh + (size_t)2048 * 1024;
  unsigned short* wgh = wvl + (size_t)2048 * 1024;
  unsigned short* wgl = wgh + (size_t)2048 * 1024;
  unsigned short* woh = wgl + (size_t)2048 * 1024;
  unsigned short* wol = woh + (size_t)2048 * 1024;
  unsigned short* oh  = (unsigned short*)v;
  unsigned short* ol  = oh + M8 * 2048;
  float* g = q;
  float* Tbuf = (float*)d_out;   // 24 MiB scratch, dead until final GEMM

  dim3 blk(256);
  cast_all<<<dim3(16384), blk, 0, stream>>>(x, Wq, Wk, Wv, Wg, Wo,
                                            xh, xl, wqh, wql, wkh, wkl,
                                            wvh, wvl, wgh, wgl, woh, wol);

  gemm_qkv<<<dim3(32, 64), blk, 0, stream>>>(xh, xl, wqh, wql, wkh, wkl, wvh, wvl, q, kk, v);
  rope_kernel<<<dim3(16384), blk, 0, stream>>>(q, kk);
  retn_gstate<<<dim3(16, 3, 8), blk, 0, stream>>>(kk, v, Tbuf);
  retn_scan<<<dim3(2048), blk, 0, stream>>>(Tbuf);
  retn_intra<<<dim3(32, 4, 4),  blk, 0, stream>>>(q, kk, v, o);
  retn_inter2<<<dim3(16, 4, 8), blk, 0, stream>>>(q, kk, v, o, Tbuf);
  gemm_bf16s<<<dim3(16, 64), blk, 0, stream>>>(xh, xl, wgh, wgl, g, 8192, 2048, 1024);
  norm_gate_cast<<<dim3(32768), blk, 0, stream>>>(o, g, gnw, oh, ol);
  gemm_bf16s<<<dim3(8, 64),  blk, 0, stream>>>(oh, ol, woh, wol, out, 8192, 1024, 2048);
}

// Round 10
// 969.358 us; speedup vs baseline: 1.0490x; 1.0490x over previous
//
#include <hip/hip_runtime.h>
#include <cstdint>
#include <cstddef>

#define T_SEQ 2048
#define DM    1024
#define HK    256
#define HV    512
#define NH    4
#define KDIM  1024
#define VDIM  2048

typedef __attribute__((ext_vector_type(8))) short bf16x8;
typedef __attribute__((ext_vector_type(4))) float f32x4;
#define AS1 __attribute__((address_space(1)))
#define AS3 __attribute__((address_space(3)))

// ---------------- f32 -> (hi, lo) bf16 split (RNE) ---------------------------
static __device__ inline unsigned short f2bf(float f) {
  unsigned u = __float_as_uint(f);
  unsigned rnd = 0x7fffu + ((u >> 16) & 1u);
  return (unsigned short)((u + rnd) >> 16);
}
static __device__ inline float bf2f(unsigned short h) {
  unsigned u = ((unsigned)h) << 16;
  return __uint_as_float(u);
}

// -------- fused hi/lo casts for x and all 5 weights (one launch) -------------
// grid 16384: [0,8192) x | [8192,9216) Wq | [9216,10240) Wk | [10240,12288) Wv
// | [12288,14336) Wg | [14336,16384) Wo. Routing is block-uniform.
__global__ __launch_bounds__(256) void cast_all(const float* __restrict__ x,
                                                const float* __restrict__ Wq,
                                                const float* __restrict__ Wk,
                                                const float* __restrict__ Wv,
                                                const float* __restrict__ Wg,
                                                const float* __restrict__ Wo,
                                                unsigned short* __restrict__ xh,  unsigned short* __restrict__ xl,
                                                unsigned short* __restrict__ wqh, unsigned short* __restrict__ wql,
                                                unsigned short* __restrict__ wkh, unsigned short* __restrict__ wkl,
                                                unsigned short* __restrict__ wvh, unsigned short* __restrict__ wvl,
                                                unsigned short* __restrict__ wgh, unsigned short* __restrict__ wgl,
                                                unsigned short* __restrict__ woh, unsigned short* __restrict__ wol) {
  const int bx = blockIdx.x;
  const float* in; unsigned short* hi; unsigned short* lo; int rel;
  if (bx < 8192)       { in = x;  hi = xh;  lo = xl;  rel = bx; }
  else if (bx < 9216)  { in = Wq; hi = wqh; lo = wql; rel = bx - 8192; }
  else if (bx < 10240) { in = Wk; hi = wkh; lo = wkl; rel = bx - 9216; }
  else if (bx < 12288) { in = Wv; hi = wvh; lo = wvl; rel = bx - 10240; }
  else if (bx < 14336) { in = Wg; hi = wgh; lo = wgl; rel = bx - 12288; }
  else                 { in = Wo; hi = woh; lo = wol; rel = bx - 14336; }
  int i = rel * 256 + threadIdx.x;          // all segments are exact multiples
  float4 v = ((const float4*)in)[i];
  ushort4 h, l;
  h.x = f2bf(v.x); l.x = f2bf(v.x - bf2f(h.x));
  h.y = f2bf(v.y); l.y = f2bf(v.y - bf2f(h.y));
  h.z = f2bf(v.z); l.z = f2bf(v.z - bf2f(h.z));
  h.w = f2bf(v.w); l.w = f2bf(v.w - bf2f(h.w));
  ((ushort4*)hi)[i] = h;
  ((ushort4*)lo)[i] = l;
}

// -------- split-precision bf16 MFMA GEMM: C = A @ W^T, A=Ah+Al, W=Wh+Wl ------
// C ~= Ah*Wh + Ah*Wl + Al*Wh (f32 accumulate; lo*lo term ~2^-16 rel, dropped).
// 128x128 tile, BK=32, 4 waves 2x2, wave = 64x64 = 4x4 16x16x32 frags.
__global__ __launch_bounds__(256) void gemm_bf16s(const unsigned short* __restrict__ Ah,
                                                  const unsigned short* __restrict__ Al,
                                                  const unsigned short* __restrict__ Wh,
                                                  const unsigned short* __restrict__ Wl,
                                                  float* __restrict__ C,
                                                  int M, int N, int K) {
  __shared__ unsigned short AhS[128 * 32];
  __shared__ unsigned short AlS[128 * 32];
  __shared__ unsigned short WhS[128 * 32];
  __shared__ unsigned short WlS[128 * 32];
  const int t = threadIdx.x;
  const int l = t & 63;
  const int w = t >> 6;
  const int bm = blockIdx.y * 128;
  const int bn = blockIdx.x * 128;
  const int wm = (w >> 1) * 64;
  const int wn = (w & 1) * 64;

  f32x4 acc[4][4];
#pragma unroll
  for (int i = 0; i < 4; ++i)
#pragma unroll
    for (int j = 0; j < 4; ++j)
#pragma unroll
      for (int r = 0; r < 4; ++r) acc[i][j][r] = 0.f;

  const int srow = w * 32 + (l >> 2);
  const int scol = (l & 3) * 8;
  const size_t gOffA = (size_t)(bm + srow) * K + scol;
  const size_t gOffW = (size_t)(bn + srow) * K + scol;
  const size_t rowStep = (size_t)16 * K;
  unsigned short* lAh0 = &AhS[(w * 32) * 32];
  unsigned short* lAh1 = &AhS[(w * 32 + 16) * 32];
  unsigned short* lAl0 = &AlS[(w * 32) * 32];
  unsigned short* lAl1 = &AlS[(w * 32 + 16) * 32];
  unsigned short* lWh0 = &WhS[(w * 32) * 32];
  unsigned short* lWh1 = &WhS[(w * 32 + 16) * 32];
  unsigned short* lWl0 = &WlS[(w * 32) * 32];
  unsigned short* lWl1 = &WlS[(w * 32 + 16) * 32];

  for (int k0 = 0; k0 < K; k0 += 32) {
    __syncthreads();
    __builtin_amdgcn_global_load_lds((const AS1 void*)(Ah + gOffA + k0),           (AS3 void*)lAh0, 16, 0, 0);
    __builtin_amdgcn_global_load_lds((const AS1 void*)(Ah + gOffA + rowStep + k0), (AS3 void*)lAh1, 16, 0, 0);
    __builtin_amdgcn_global_load_lds((const AS1 void*)(Al + gOffA + k0),           (AS3 void*)lAl0, 16, 0, 0);
    __builtin_amdgcn_global_load_lds((const AS1 void*)(Al + gOffA + rowStep + k0), (AS3 void*)lAl1, 16, 0, 0);
    __builtin_amdgcn_global_load_lds((const AS1 void*)(Wh + gOffW + k0),           (AS3 void*)lWh0, 16, 0, 0);
    __builtin_amdgcn_global_load_lds((const AS1 void*)(Wh + gOffW + rowStep + k0), (AS3 void*)lWh1, 16, 0, 0);
    __builtin_amdgcn_global_load_lds((const AS1 void*)(Wl + gOffW + k0),           (AS3 void*)lWl0, 16, 0, 0);
    __builtin_amdgcn_global_load_lds((const AS1 void*)(Wl + gOffW + rowStep + k0), (AS3 void*)lWl1, 16, 0, 0);
    __syncthreads();

    bf16x8 ah[4], al[4], bh[4], bl[4];
#pragma unroll
    for (int i = 0; i < 4; ++i) {
      int aoff = (wm + i * 16 + (l & 15)) * 32 + (l >> 4) * 8;
      int boff = (wn + i * 16 + (l & 15)) * 32 + (l >> 4) * 8;
      ah[i] = *(const bf16x8*)&AhS[aoff];
      al[i] = *(const bf16x8*)&AlS[aoff];
      bh[i] = *(const bf16x8*)&WhS[boff];
      bl[i] = *(const bf16x8*)&WlS[boff];
    }
#pragma unroll
    for (int i = 0; i < 4; ++i)
#pragma unroll
      for (int j = 0; j < 4; ++j) {
        acc[i][j] = __builtin_amdgcn_mfma_f32_16x16x32_bf16(ah[i], bh[j], acc[i][j], 0, 0, 0);
        acc[i][j] = __builtin_amdgcn_mfma_f32_16x16x32_bf16(ah[i], bl[j], acc[i][j], 0, 0, 0);
        acc[i][j] = __builtin_amdgcn_mfma_f32_16x16x32_bf16(al[i], bh[j], acc[i][j], 0, 0, 0);
      }
  }

  const int cr = (l >> 4) * 4;
  const int cc = l & 15;
#pragma unroll
  for (int i = 0; i < 4; ++i)
#pragma unroll
    for (int j = 0; j < 4; ++j)
#pragma unroll
      for (int r = 0; r < 4; ++r)
        C[(size_t)(bm + wm + i * 16 + cr + r) * N + (bn + wn + j * 16 + cc)] = acc[i][j][r];
}

// -------- merged q/k/v projection GEMM (one launch, routed by blockIdx.x) ----
__global__ __launch_bounds__(256) void gemm_qkv(const unsigned short* __restrict__ Ah,
                                                const unsigned short* __restrict__ Al,
                                                const unsigned short* __restrict__ wqh,
                                                const unsigned short* __restrict__ wql,
                                                const unsigned short* __restrict__ wkh,
                                                const unsigned short* __restrict__ wkl,
                                                const unsigned short* __restrict__ wvh,
                                                const unsigned short* __restrict__ wvl,
                                                float* __restrict__ q,
                                                float* __restrict__ kk,
                                                float* __restrict__ v) {
  const int K = 1024;
  const int bx = blockIdx.x;
  const unsigned short* Wh; const unsigned short* Wl; float* C; int N; int bn;
  if (bx < 8)       { Wh = wqh; Wl = wql; C = q;  N = 1024; bn = bx * 128; }
  else if (bx < 16) { Wh = wkh; Wl = wkl; C = kk; N = 1024; bn = (bx - 8) * 128; }
  else              { Wh = wvh; Wl = wvl; C = v;  N = 2048; bn = (bx - 16) * 128; }

  __shared__ unsigned short AhS[128 * 32];
  __shared__ unsigned short AlS[128 * 32];
  __shared__ unsigned short WhS[128 * 32];
  __shared__ unsigned short WlS[128 * 32];
  const int t = threadIdx.x;
  const int l = t & 63;
  const int w = t >> 6;
  const int bm = blockIdx.y * 128;
  const int wm = (w >> 1) * 64;
  const int wn = (w & 1) * 64;

  f32x4 acc[4][4];
#pragma unroll
  for (int i = 0; i < 4; ++i)
#pragma unroll
    for (int j = 0; j < 4; ++j)
#pragma unroll
      for (int r = 0; r < 4; ++r) acc[i][j][r] = 0.f;

  const int srow = w * 32 + (l >> 2);
  const int scol = (l & 3) * 8;
  const size_t gOffA = (size_t)(bm + srow) * K + scol;
  const size_t gOffW = (size_t)(bn + srow) * K + scol;
  const size_t rowStep = (size_t)16 * K;
  unsigned short* lAh0 = &AhS[(w * 32) * 32];
  unsigned short* lAh1 = &AhS[(w * 32 + 16) * 32];
  unsigned short* lAl0 = &AlS[(w * 32) * 32];
  unsigned short* lAl1 = &AlS[(w * 32 + 16) * 32];
  unsigned short* lWh0 = &WhS[(w * 32) * 32];
  unsigned short* lWh1 = &WhS[(w * 32 + 16) * 32];
  unsigned short* lWl0 = &WlS[(w * 32) * 32];
  unsigned short* lWl1 = &WlS[(w * 32 + 16) * 32];

  for (int k0 = 0; k0 < K; k0 += 32) {
    __syncthreads();
    __builtin_amdgcn_global_load_lds((const AS1 void*)(Ah + gOffA + k0),           (AS3 void*)lAh0, 16, 0, 0);
    __builtin_amdgcn_global_load_lds((const AS1 void*)(Ah + gOffA + rowStep + k0), (AS3 void*)lAh1, 16, 0, 0);
    __builtin_amdgcn_global_load_lds((const AS1 void*)(Al + gOffA + k0),           (AS3 void*)lAl0, 16, 0, 0);
    __builtin_amdgcn_global_load_lds((const AS1 void*)(Al + gOffA + rowStep + k0), (AS3 void*)lAl1, 16, 0, 0);
    __builtin_amdgcn_global_load_lds((const AS1 void*)(Wh + gOffW + k0),           (AS3 void*)lWh0, 16, 0, 0);
    __builtin_amdgcn_global_load_lds((const AS1 void*)(Wh + gOffW + rowStep + k0), (AS3 void*)lWh1, 16, 0, 0);
    __builtin_amdgcn_global_load_lds((const AS1 void*)(Wl + gOffW + k0),           (AS3 void*)lWl0, 16, 0, 0);
    __builtin_amdgcn_global_load_lds((const AS1 void*)(Wl + gOffW + rowStep + k0), (AS3 void*)lWl1, 16, 0, 0);
    __syncthreads();

    bf16x8 ah[4], al[4], bh[4], bl[4];
#pragma unroll
    for (int i = 0; i < 4; ++i) {
      int aoff = (wm + i * 16 + (l & 15)) * 32 + (l >> 4) * 8;
      int boff = (wn + i * 16 + (l & 15)) * 32 + (l >> 4) * 8;
      ah[i] = *(const bf16x8*)&AhS[aoff];
      al[i] = *(const bf16x8*)&AlS[aoff];
      bh[i] = *(const bf16x8*)&WhS[boff];
      bl[i] = *(const bf16x8*)&WlS[boff];
    }
#pragma unroll
    for (int i = 0; i < 4; ++i)
#pragma unroll
      for (int j = 0; j < 4; ++j) {
        acc[i][j] = __builtin_amdgcn_mfma_f32_16x16x32_bf16(ah[i], bh[j], acc[i][j], 0, 0, 0);
        acc[i][j] = __builtin_amdgcn_mfma_f32_16x16x32_bf16(ah[i], bl[j], acc[i][j], 0, 0, 0);
        acc[i][j] = __builtin_amdgcn_mfma_f32_16x16x32_bf16(al[i], bh[j], acc[i][j], 0, 0, 0);
      }
  }

  const int cr = (l >> 4) * 4;
  const int cc = l & 15;
#pragma unroll
  for (int i = 0; i < 4; ++i)
#pragma unroll
    for (int j = 0; j < 4; ++j)
#pragma unroll
      for (int r = 0; r < 4; ++r)
        C[(size_t)(bm + wm + i * 16 + cr + r) * N + (bn + wn + j * 16 + cc)] = acc[i][j][r];
}

// ---------------- RoPE trig table: tab[tt*128+f] = (cos, sin) ----------------
// Same per-(tt,f) computation as the old in-kernel trig -> bitwise identical.
__global__ __launch_bounds__(256) void rope_tab(float2* __restrict__ tab) {
  int i = blockIdx.x * 256 + threadIdx.x;   // 262144 = 2048 * 128
  int f  = i & 127;
  int tt = i >> 7;
  float invf = powf(10000.0f, -(float)f * (1.0f / 128.0f));
  float ang  = (float)tt * invf;
  float s, c;
  sincosf(ang, &s, &c);
  tab[i] = make_float2(c, s);
}

// ---------------- RoPE (in-place on q and k), q also scaled by HK^-0.5 -------
// Trig from precomputed table (2 MB, L2-resident) -> memory-bound.
__global__ __launch_bounds__(256) void rope_kernel(float* __restrict__ q,
                                                   float* __restrict__ k,
                                                   const float2* __restrict__ tab) {
  int idx = blockIdx.x * 256 + threadIdx.x;     // over B*T*H*128 = 4,194,304
  int f  = idx & 127;
  int h  = (idx >> 7) & 3;
  int tt = (idx >> 9) & 2047;
  int b  = idx >> 20;
  size_t a0 = ((size_t)(b * T_SEQ + tt)) * KDIM + h * HK + f;
  size_t a1 = a0 + 128;
  float2 cs = tab[tt * 128 + f];
  float c = cs.x, s = cs.y;
  float q1 = q[a0], q2 = q[a1];
  q[a0] = (q1 * c - q2 * s) * 0.0625f;
  q[a1] = (q2 * c + q1 * s) * 0.0625f;
  float k1 = k[a0], k2 = k[a1];
  k[a0] = k1 * c - k2 * s;
  k[a1] = k2 * c + k1 * s;
}

// ---------------- Retention pass 1: intra-chunk (fully parallel) -------------
__global__ __launch_bounds__(256) void retn_intra(const float* __restrict__ q,
                                                  const float* __restrict__ k,
                                                  const float* __restrict__ v,
                                                  float* __restrict__ o) {
  const int n = blockIdx.x, h = blockIdx.y, b = blockIdx.z;
  const int t = threadIdx.x;
  const int t0 = n * 64;
  __shared__ float gpow[65];
  __shared__ __align__(16) float qS[64][68];
  __shared__ __align__(16) float kS[64][68];
  __shared__ __align__(16) float attnS[64][68];
  if (t <= 64) {
    float gamma = 1.0f - exp2f(-5.0f - (float)h);
    gpow[t] = powf(gamma, (float)t);
  }
  const size_t baseQK = (size_t)(b * T_SEQ + t0) * KDIM + h * HK;
  const size_t baseV  = (size_t)(b * T_SEQ + t0) * VDIM + h * HV;
  const int i0 = (t >> 4) * 4;
  const int j0 = (t & 15) * 4;
  float acc[4][4] = {};
  for (int s = 0; s < 4; ++s) {              // dk slices of 64
    __syncthreads();
    __builtin_amdgcn_sched_barrier(0);
#pragma unroll
    for (int r = 0; r < 4; ++r) {            // stage 64x64 as float4
      int idx = t + 256 * r;
      int row = idx >> 4, c4 = (idx & 15) * 4;
      *(float4*)&qS[row][c4] = *(const float4*)&q[baseQK + (size_t)row * KDIM + s * 64 + c4];
      *(float4*)&kS[row][c4] = *(const float4*)&k[baseQK + (size_t)row * KDIM + s * 64 + c4];
    }
    __syncthreads();
    __builtin_amdgcn_sched_barrier(0);
    for (int d = 0; d < 64; d += 4) {
      float4 a0 = *(const float4*)&qS[i0 + 0][d];
      float4 a1 = *(const float4*)&qS[i0 + 1][d];
      float4 a2 = *(const float4*)&qS[i0 + 2][d];
      float4 a3 = *(const float4*)&qS[i0 + 3][d];
      float4 b0 = *(const float4*)&kS[j0 + 0][d];
      float4 b1 = *(const float4*)&kS[j0 + 1][d];
      float4 b2 = *(const float4*)&kS[j0 + 2][d];
      float4 b3 = *(const float4*)&kS[j0 + 3][d];
      acc[0][0]=fmaf(a0.x,b0.x,acc[0][0]); acc[0][0]=fmaf(a0.y,b0.y,acc[0][0]); acc[0][0]=fmaf(a0.z,b0.z,acc[0][0]); acc[0][0]=fmaf(a0.w,b0.w,acc[0][0]);
      acc[0][1]=fmaf(a0.x,b1.x,acc[0][1]); acc[0][1]=fmaf(a0.y,b1.y,acc[0][1]); acc[0][1]=fmaf(a0.z,b1.z,acc[0][1]); acc[0][1]=fmaf(a0.w,b1.w,acc[0][1]);
      acc[0][2]=fmaf(a0.x,b2.x,acc[0][2]); acc[0][2]=fmaf(a0.y,b2.y,acc[0][2]); acc[0][2]=fmaf(a0.z,b2.z,acc[0][2]); acc[0][2]=fmaf(a0.w,b2.w,acc[0][2]);
      acc[0][3]=fmaf(a0.x,b3.x,acc[0][3]); acc[0][3]=fmaf(a0.y,b3.y,acc[0][3]); acc[0][3]=fmaf(a0.z,b3.z,acc[0][3]); acc[0][3]=fmaf(a0.w,b3.w,acc[0][3]);
      acc[1][0]=fmaf(a1.x,b0.x,acc[1][0]); acc[1][0]=fmaf(a1.y,b0.y,acc[1][0]); acc[1][0]=fmaf(a1.z,b0.z,acc[1][0]); acc[1][0]=fmaf(a1.w,b0.w,acc[1][0]);
      acc[1][1]=fmaf(a1.x,b1.x,acc[1][1]); acc[1][1]=fmaf(a1.y,b1.y,acc[1][1]); acc[1][1]=fmaf(a1.z,b1.z,acc[1][1]); acc[1][1]=fmaf(a1.w,b1.w,acc[1][1]);
      acc[1][2]=fmaf(a1.x,b2.x,acc[1][2]); acc[1][2]=fmaf(a1.y,b2.y,acc[1][2]); acc[1][2]=fmaf(a1.z,b2.z,acc[1][2]); acc[1][2]=fmaf(a1.w,b2.w,acc[1][2]);
      acc[1][3]=fmaf(a1.x,b3.x,acc[1][3]); acc[1][3]=fmaf(a1.y,b3.y,acc[1][3]); acc[1][3]=fmaf(a1.z,b3.z,acc[1][3]); acc[1][3]=fmaf(a1.w,b3.w,acc[1][3]);
      acc[2][0]=fmaf(a2.x,b0.x,acc[2][0]); acc[2][0]=fmaf(a2.y,b0.y,acc[2][0]); acc[2][0]=fmaf(a2.z,b0.z,acc[2][0]); acc[2][0]=fmaf(a2.w,b0.w,acc[2][0]);
      acc[2][1]=fmaf(a2.x,b1.x,acc[2][1]); acc[2][1]=fmaf(a2.y,b1.y,acc[2][1]); acc[2][1]=fmaf(a2.z,b1.z,acc[2][1]); acc[2][1]=fmaf(a2.w,b1.w,acc[2][1]);
      acc[2][2]=fmaf(a2.x,b2.x,acc[2][2]); acc[2][2]=fmaf(a2.y,b2.y,acc[2][2]); acc[2][2]=fmaf(a2.z,b2.z,acc[2][2]); acc[2][2]=fmaf(a2.w,b2.w,acc[2][2]);
      acc[2][3]=fmaf(a2.x,b3.x,acc[2][3]); acc[2][3]=fmaf(a2.y,b3.y,acc[2][3]); acc[2][3]=fmaf(a2.z,b3.z,acc[2][3]); acc[2][3]=fmaf(a2.w,b3.w,acc[2][3]);
      acc[3][0]=fmaf(a3.x,b0.x,acc[3][0]); acc[3][0]=fmaf(a3.y,b0.y,acc[3][0]); acc[3][0]=fmaf(a3.z,b0.z,acc[3][0]); acc[3][0]=fmaf(a3.w,b0.w,acc[3][0]);
      acc[3][1]=fmaf(a3.x,b1.x,acc[3][1]); acc[3][1]=fmaf(a3.y,b1.y,acc[3][1]); acc[3][1]=fmaf(a3.z,b1.z,acc[3][1]); acc[3][1]=fmaf(a3.w,b1.w,acc[3][1]);
      acc[3][2]=fmaf(a3.x,b2.x,acc[3][2]); acc[3][2]=fmaf(a3.y,b2.y,acc[3][2]); acc[3][2]=fmaf(a3.z,b2.z,acc[3][2]); acc[3][2]=fmaf(a3.w,b2.w,acc[3][2]);
      acc[3][3]=fmaf(a3.x,b3.x,acc[3][3]); acc[3][3]=fmaf(a3.y,b3.y,acc[3][3]); acc[3][3]=fmaf(a3.z,b3.z,acc[3][3]); acc[3][3]=fmaf(a3.w,b3.w,acc[3][3]);
    }
  }
  __syncthreads();
#pragma unroll
  for (int ii = 0; ii < 4; ++ii)
#pragma unroll
    for (int jj = 0; jj < 4; ++jj) {
      int i = i0 + ii, j = j0 + jj;
      attnS[i][j] = (i >= j) ? acc[ii][jj] * gpow[i - j] : 0.0f;
    }
  float (*vS)[68] = qS;
  for (int vb = 0; vb < 8; ++vb) {
    __syncthreads();
    __builtin_amdgcn_sched_barrier(0);
#pragma unroll
    for (int r = 0; r < 4; ++r) {
      int idx = t + 256 * r;
      int row = idx >> 4, c4 = (idx & 15) * 4;
      *(float4*)&vS[row][c4] = *(const float4*)&v[baseV + (size_t)row * VDIM + vb * 64 + c4];
    }
    __syncthreads();
    __builtin_amdgcn_sched_barrier(0);
    float oa[4][4] = {};
    for (int j = 0; j < 64; j += 4) {
      float4 p0 = *(const float4*)&attnS[i0 + 0][j];
      float4 p1 = *(const float4*)&attnS[i0 + 1][j];
      float4 p2 = *(const float4*)&attnS[i0 + 2][j];
      float4 p3 = *(const float4*)&attnS[i0 + 3][j];
      float4 v0 = *(const float4*)&vS[j + 0][j0];
      float4 v1 = *(const float4*)&vS[j + 1][j0];
      float4 v2 = *(const float4*)&vS[j + 2][j0];
      float4 v3 = *(const float4*)&vS[j + 3][j0];
      oa[0][0]=fmaf(p0.x,v0.x,oa[0][0]); oa[0][0]=fmaf(p0.y,v1.x,oa[0][0]); oa[0][0]=fmaf(p0.z,v2.x,oa[0][0]); oa[0][0]=fmaf(p0.w,v3.x,oa[0][0]);
      oa[0][1]=fmaf(p0.x,v0.y,oa[0][1]); oa[0][1]=fmaf(p0.y,v1.y,oa[0][1]); oa[0][1]=fmaf(p0.z,v2.y,oa[0][1]); oa[0][1]=fmaf(p0.w,v3.y,oa[0][1]);
      oa[0][2]=fmaf(p0.x,v0.z,oa[0][2]); oa[0][2]=fmaf(p0.y,v1.z,oa[0][2]); oa[0][2]=fmaf(p0.z,v2.z,oa[0][2]); oa[0][2]=fmaf(p0.w,v3.z,oa[0][2]);
      oa[0][3]=fmaf(p0.x,v0.w,oa[0][3]); oa[0][3]=fmaf(p0.y,v1.w,oa[0][3]); oa[0][3]=fmaf(p0.z,v2.w,oa[0][3]); oa[0][3]=fmaf(p0.w,v3.w,oa[0][3]);
      oa[1][0]=fmaf(p1.x,v0.x,oa[1][0]); oa[1][0]=fmaf(p1.y,v1.x,oa[1][0]); oa[1][0]=fmaf(p1.z,v2.x,oa[1][0]); oa[1][0]=fmaf(p1.w,v3.x,oa[1][0]);
      oa[1][1]=fmaf(p1.x,v0.y,oa[1][1]); oa[1][1]=fmaf(p1.y,v1.y,oa[1][1]); oa[1][1]=fmaf(p1.z,v2.y,oa[1][1]); oa[1][1]=fmaf(p1.w,v3.y,oa[1][1]);
      oa[1][2]=fmaf(p1.x,v0.z,oa[1][2]); oa[1][2]=fmaf(p1.y,v1.z,oa[1][2]); oa[1][2]=fmaf(p1.z,v2.z,oa[1][2]); oa[1][2]=fmaf(p1.w,v3.z,oa[1][2]);
      oa[1][3]=fmaf(p1.x,v0.w,oa[1][3]); oa[1][3]=fmaf(p1.y,v1.w,oa[1][3]); oa[1][3]=fmaf(p1.z,v2.w,oa[1][3]); oa[1][3]=fmaf(p1.w,v3.w,oa[1][3]);
      oa[2][0]=fmaf(p2.x,v0.x,oa[2][0]); oa[2][0]=fmaf(p2.y,v1.x,oa[2][0]); oa[2][0]=fmaf(p2.z,v2.x,oa[2][0]); oa[2][0]=fmaf(p2.w,v3.x,oa[2][0]);
      oa[2][1]=fmaf(p2.x,v0.y,oa[2][1]); oa[2][1]=fmaf(p2.y,v1.y,oa[2][1]); oa[2][1]=fmaf(p2.z,v2.y,oa[2][1]); oa[2][1]=fmaf(p2.w,v3.y,oa[2][1]);
      oa[2][2]=fmaf(p2.x,v0.z,oa[2][2]); oa[2][2]=fmaf(p2.y,v1.z,oa[2][2]); oa[2][2]=fmaf(p2.z,v2.z,oa[2][2]); oa[2][2]=fmaf(p2.w,v3.z,oa[2][2]);
      oa[2][3]=fmaf(p2.x,v0.w,oa[2][3]); oa[2][3]=fmaf(p2.y,v1.w,oa[2][3]); oa[2][3]=fmaf(p2.z,v2.w,oa[2][3]); oa[2][3]=fmaf(p2.w,v3.w,oa[2][3]);
      oa[3][0]=fmaf(p3.x,v0.x,oa[3][0]); oa[3][0]=fmaf(p3.y,v1.x,oa[3][0]); oa[3][0]=fmaf(p3.z,v2.x,oa[3][0]); oa[3][0]=fmaf(p3.w,v3.x,oa[3][0]);
      oa[3][1]=fmaf(p3.x,v0.y,oa[3][1]); oa[3][1]=fmaf(p3.y,v1.y,oa[3][1]); oa[3][1]=fmaf(p3.z,v2.y,oa[3][1]); oa[3][1]=fmaf(p3.w,v3.y,oa[3][1]);
      oa[3][2]=fmaf(p3.x,v0.z,oa[3][2]); oa[3][2]=fmaf(p3.y,v1.z,oa[3][2]); oa[3][2]=fmaf(p3.z,v2.z,oa[3][2]); oa[3][2]=fmaf(p3.w,v3.z,oa[3][2]);
      oa[3][3]=fmaf(p3.x,v0.w,oa[3][3]); oa[3][3]=fmaf(p3.y,v1.w,oa[3][3]); oa[3][3]=fmaf(p3.z,v2.w,oa[3][3]); oa[3][3]=fmaf(p3.w,v3.w,oa[3][3]);
    }
#pragma unroll
    for (int ii = 0; ii < 4; ++ii)
      *(float4*)&o[baseV + (size_t)(i0 + ii) * VDIM + vb * 64 + j0] =
          make_float4(oa[ii][0], oa[ii][1], oa[ii][2], oa[ii][3]);
  }
}

// =================== Retention inter-chunk: two-level scan ===================
// ROUND-10: resubmission of round-9 (bench infra failed; no counters). T14
// async-STAGE split on retn_inter2 (issue next-b4 q/k global loads during
// current compute; only the ds_write remains in the stage slot) + T5 setprio
// around the compute clusters. Barrier count/positions and math order
// unchanged from the verified round-8 kernel.

// ---- pass A: group-local state sums (128x128 tiles) -----------------------
__global__ __launch_bounds__(256) void retn_gstate(const float* __restrict__ k,
                                                   const float* __restrict__ v,
                                                   float* __restrict__ Tbuf) {
  // grid (16, 3, 8): x = b*4+h, y = g (0..2), z: dkt = z>>2 (0..1), dvt = z&3
  const int bh = blockIdx.x; const int b = bh >> 2, h = bh & 3;
  const int g = blockIdx.y;
  const int dkt = blockIdx.z >> 2, dvt = blockIdx.z & 3;
  const int t = threadIdx.x;
  __shared__ float gpow[65];
  __shared__ __align__(16) float kS[64][132];
  __shared__ __align__(16) float vS[64][132];
  if (t <= 64) gpow[t] = powf(1.0f - exp2f(-5.0f - (float)h), (float)t);
  __syncthreads();
  const float gC = gpow[64];
  const size_t baseK = (size_t)(b * T_SEQ + g * 512) * KDIM + h * HK + dkt * 128;
  const size_t baseV = (size_t)(b * T_SEQ + g * 512) * VDIM + h * HV + dvt * 128;
  const int dk0 = (t & 15) * 4;   // dk rows: dk0..+3 and dk0+64..+67
  const int c0  = (t >> 4) * 4;   // dv cols: c0..+3  and c0+64..+67
  // S: 64 regs, compile-time indices only, never address-taken.
  float S[2][2][4][4] = {};       // [dk-half][dv-half][dk-sub][dv-sub]
  for (int c = 0; c < 8; ++c) {
    const int t0 = c * 64;
    __syncthreads();
    __builtin_amdgcn_sched_barrier(0);
#pragma unroll
    for (int r = 0; r < 8; ++r) {           // stage 64x128 k~ and v as float4
      int idx = t + 256 * r; int row = idx >> 5, c4 = (idx & 31) * 4;
      float4 kv = *(const float4*)&k[baseK + (size_t)(t0 + row) * KDIM + c4];
      float kd = gpow[63 - row];
      kv.x *= kd; kv.y *= kd; kv.z *= kd; kv.w *= kd;
      *(float4*)&kS[row][c4] = kv;
      *(float4*)&vS[row][c4] = *(const float4*)&v[baseV + (size_t)(t0 + row) * VDIM + c4];
    }
    __syncthreads();
    __builtin_amdgcn_sched_barrier(0);
    __builtin_amdgcn_s_setprio(1);
#pragma unroll
    for (int p = 0; p < 2; ++p)
#pragma unroll
      for (int qh = 0; qh < 2; ++qh)
#pragma unroll
        for (int ii = 0; ii < 4; ++ii)
#pragma unroll
          for (int jj = 0; jj < 4; ++jj) S[p][qh][ii][jj] *= gC;
    for (int j = 0; j < 64; ++j) {
      float4 ka = *(const float4*)&kS[j][dk0];
      float4 kb = *(const float4*)&kS[j][dk0 + 64];
      float4 va = *(const float4*)&vS[j][c0];
      float4 vb = *(const float4*)&vS[j][c0 + 64];
      float kr[8] = {ka.x, ka.y, ka.z, ka.w, kb.x, kb.y, kb.z, kb.w};
      float vr[8] = {va.x, va.y, va.z, va.w, vb.x, vb.y, vb.z, vb.w};
#pragma unroll
      for (int ii = 0; ii < 8; ++ii)
#pragma unroll
        for (int jj = 0; jj < 8; ++jj)
          S[ii >> 2][jj >> 2][ii & 3][jj & 3] =
              fmaf(kr[ii], vr[jj], S[ii >> 2][jj >> 2][ii & 3][jj & 3]);
    }
    __builtin_amdgcn_s_setprio(0);
  }
  const size_t tbRow = ((size_t)g * 16 + bh) * 256 + dkt * 128 + dk0;
  const size_t tbCol = (size_t)dvt * 128 + c0;
#pragma unroll
  for (int p = 0; p < 2; ++p)
#pragma unroll
    for (int ii = 0; ii < 4; ++ii) {
      size_t rowb = (tbRow + p * 64 + ii) * 512 + tbCol;
      *(float4*)&Tbuf[rowb]      = make_float4(S[p][0][ii][0], S[p][0][ii][1], S[p][0][ii][2], S[p][0][ii][3]);
      *(float4*)&Tbuf[rowb + 64] = make_float4(S[p][1][ii][0], S[p][1][ii][1], S[p][1][ii][2], S[p][1][ii][3]);
    }
}

// ---- pass B: exclusive scan over the 4 groups (in-place) ------------------
__global__ __launch_bounds__(256) void retn_scan(float* __restrict__ Tbuf) {
  int i = blockIdx.x * 256 + threadIdx.x;   // float4 index within one g-slab
  int h = (i >> 15) & 3;                    // (i*4)>>17 & 3
  float gamma = 1.0f - exp2f(-5.0f - (float)h);
  float gG = powf(gamma, 512.0f);           // gC^8 = gamma^(64*8)
  float4* T = (float4*)Tbuf;
  const int slab = 524288;                  // 16*256*512/4
  float4 t0 = T[i], t1 = T[i + slab], t2 = T[i + 2 * slab];
  float4 s2, s3;
  s2.x = fmaf(gG, t0.x, t1.x); s2.y = fmaf(gG, t0.y, t1.y);
  s2.z = fmaf(gG, t0.z, t1.z); s2.w = fmaf(gG, t0.w, t1.w);
  s3.x = fmaf(gG, s2.x, t2.x); s3.y = fmaf(gG, s2.y, t2.y);
  s3.z = fmaf(gG, s2.z, t2.z); s3.w = fmaf(gG, s2.w, t2.w);
  T[i + slab] = s2; T[i + 2 * slab] = s3;
}

// ---- pass C: inter-chunk output, full-dk state in regs, no atomics --------
__global__ __launch_bounds__(256) void retn_inter2(const float* __restrict__ q,
                                                   const float* __restrict__ k,
                                                   const float* __restrict__ v,
                                                   float* __restrict__ o,
                                                   const float* __restrict__ Sbuf) {
  // grid (16, 4, 8): x = b*4+h, y = g, z = dvt (64-wide dv tiles)
  const int bh = blockIdx.x; const int b = bh >> 2, h = bh & 3;
  const int g = blockIdx.y;
  const int dvt = blockIdx.z;
  const int t = threadIdx.x;
  __shared__ float gpow[65];
  __shared__ __align__(16) float qS[64][68];  // q~ block (64x64)
  __shared__ __align__(16) float kS[64][68];  // k~ block (64x64)
  __shared__ __align__(16) float sS[64][68];  // state-block publish (64x64)
  __shared__ __align__(16) float vS[64][68];  // v chunk (64x64)
  if (t <= 64) gpow[t] = powf(1.0f - exp2f(-5.0f - (float)h), (float)t);
  __syncthreads();
  const float gC = gpow[64];
  const int rq = (t & 15) * 4;   // state rows within a dk-block (publish/j-loop)
  const int c0 = (t >> 4) * 4;   // state cols (0,4,..,60)
  const int i0 = (t >> 4) * 4;   // o-tile rows
  const int v0 = (t & 15) * 4;   // o-tile cols
  const size_t baseQK = (size_t)(b * T_SEQ + g * 512) * KDIM + h * HK;
  const size_t baseV  = (size_t)(b * T_SEQ + g * 512) * VDIM + h * HV + (size_t)dvt * 64;
  // per-thread staging coordinates (row/col pattern shared by all stages)
  const int srow0 = t >> 4;            // + 16*r
  const int scol  = (t & 15) * 4;

  // S: 64 regs/thread, compile-time indices only, never address-taken.
  float S[4][4][4];              // [dk-block][row][col]; cols c0..c0+3
  if (g > 0) {
    const size_t sb = (((size_t)(g - 1) * 16 + bh) * 256) * 512 + (size_t)dvt * 64 + c0;
#pragma unroll
    for (int b4 = 0; b4 < 4; ++b4)
#pragma unroll
      for (int i = 0; i < 4; ++i) {
        float4 tmp = *(const float4*)&Sbuf[sb + (size_t)(b4 * 64 + rq + i) * 512];
        S[b4][i][0] = tmp.x; S[b4][i][1] = tmp.y; S[b4][i][2] = tmp.z; S[b4][i][3] = tmp.w;
      }
  } else {
#pragma unroll
    for (int b4 = 0; b4 < 4; ++b4)
#pragma unroll
      for (int i = 0; i < 4; ++i) {
        S[b4][i][0] = 0.f; S[b4][i][1] = 0.f; S[b4][i][2] = 0.f; S[b4][i][3] = 0.f;
      }
  }

  float4 pq[4], pk[4];           // prefetched q/k rows for the NEXT b4 phase

  for (int c = 0; c < 8; ++c) {
    const int t0 = c * 64;
    const bool doO = (g > 0 || c > 0);     // block-uniform; S==0 otherwise
    __syncthreads();                       // prev chunk's vS readers done
    __builtin_amdgcn_sched_barrier(0);
#pragma unroll
    for (int r = 0; r < 4; ++r) {          // stage v chunk 64x64
      int row = srow0 + 16 * r;
      *(float4*)&vS[row][scol] = *(const float4*)&v[baseV + (size_t)(t0 + row) * VDIM + scol];
    }
    // T14: issue b4=0's q/k loads now; latency overlaps barrier + publish.
#pragma unroll
    for (int r = 0; r < 4; ++r) {
      int row = srow0 + 16 * r;
      pq[r] = *(const float4*)&q[baseQK + (size_t)(t0 + row) * KDIM + 0 * 64 + scol];
      pk[r] = *(const float4*)&k[baseQK + (size_t)(t0 + row) * KDIM + 0 * 64 + scol];
    }
    float oa[4][4] = {};
#pragma unroll
    for (int b4 = 0; b4 < 4; ++b4) {
      __syncthreads();                     // prev b4's qS/kS/sS readers done (covers vS write at b4=0)
      __builtin_amdgcn_sched_barrier(0);
      if (doO) {
        // publish this dk-block of S (OLD state) for the o-phase
#pragma unroll
        for (int i = 0; i < 4; ++i)
          *(float4*)&sS[rq + i][c0] =
              make_float4(S[b4][i][0], S[b4][i][1], S[b4][i][2], S[b4][i][3]);
        // write prefetched q~ block (loads issued one phase ago -> landed)
#pragma unroll
        for (int r = 0; r < 4; ++r) {
          int row = srow0 + 16 * r;
          float gp = gpow[row + 1];
          float4 qv = pq[r];
          qv.x *= gp; qv.y *= gp; qv.z *= gp; qv.w *= gp;
          *(float4*)&qS[row][scol] = qv;
        }
      }
      // write prefetched k~ block
#pragma unroll
      for (int r = 0; r < 4; ++r) {
        int row = srow0 + 16 * r;
        float kd = gpow[63 - row];
        float4 kv = pk[r];
        kv.x *= kd; kv.y *= kd; kv.z *= kd; kv.w *= kd;
        *(float4*)&kS[row][scol] = kv;
      }
      // T14: issue NEXT b4's loads; latency hides under barrier + compute.
      if (b4 < 3) {
#pragma unroll
        for (int r = 0; r < 4; ++r) {
          int row = srow0 + 16 * r;
          pq[r] = *(const float4*)&q[baseQK + (size_t)(t0 + row) * KDIM + (b4 + 1) * 64 + scol];
          pk[r] = *(const float4*)&k[baseQK + (size_t)(t0 + row) * KDIM + (b4 + 1) * 64 + scol];
        }
      }
      __syncthreads();
      __builtin_amdgcn_sched_barrier(0);
      __builtin_amdgcn_s_setprio(1);
      if (doO) {
        // o-phase: oa += q~S(64x64) @ sS(64x64), this thread: 4 rows x 4 cols
        for (int d = 0; d < 64; d += 4) {
          float4 a0 = *(const float4*)&qS[i0 + 0][d];
          float4 a1 = *(const float4*)&qS[i0 + 1][d];
          float4 a2 = *(const float4*)&qS[i0 + 2][d];
          float4 a3 = *(const float4*)&qS[i0 + 3][d];
          float4 s0 = *(const float4*)&sS[d + 0][v0];
          float4 s1 = *(const float4*)&sS[d + 1][v0];
          float4 s2 = *(const float4*)&sS[d + 2][v0];
          float4 s3 = *(const float4*)&sS[d + 3][v0];
          oa[0][0]=fmaf(a0.x,s0.x,oa[0][0]); oa[0][0]=fmaf(a0.y,s1.x,oa[0][0]); oa[0][0]=fmaf(a0.z,s2.x,oa[0][0]); oa[0][0]=fmaf(a0.w,s3.x,oa[0][0]);
          oa[0][1]=fmaf(a0.x,s0.y,oa[0][1]); oa[0][1]=fmaf(a0.y,s1.y,oa[0][1]); oa[0][1]=fmaf(a0.z,s2.y,oa[0][1]); oa[0][1]=fmaf(a0.w,s3.y,oa[0][1]);
          oa[0][2]=fmaf(a0.x,s0.z,oa[0][2]); oa[0][2]=fmaf(a0.y,s1.z,oa[0][2]); oa[0][2]=fmaf(a0.z,s2.z,oa[0][2]); oa[0][2]=fmaf(a0.w,s3.z,oa[0][2]);
          oa[0][3]=fmaf(a0.x,s0.w,oa[0][3]); oa[0][3]=fmaf(a0.y,s1.w,oa[0][3]); oa[0][3]=fmaf(a0.z,s2.w,oa[0][3]); oa[0][3]=fmaf(a0.w,s3.w,oa[0][3]);
          oa[1][0]=fmaf(a1.x,s0.x,oa[1][0]); oa[1][0]=fmaf(a1.y,s1.x,oa[1][0]); oa[1][0]=fmaf(a1.z,s2.x,oa[1][0]); oa[1][0]=fmaf(a1.w,s3.x,oa[1][0]);
          oa[1][1]=fmaf(a1.x,s0.y,oa[1][1]); oa[1][1]=fmaf(a1.y,s1.y,oa[1][1]); oa[1][1]=fmaf(a1.z,s2.y,oa[1][1]); oa[1][1]=fmaf(a1.w,s3.y,oa[1][1]);
          oa[1][2]=fmaf(a1.x,s0.z,oa[1][2]); oa[1][2]=fmaf(a1.y,s1.z,oa[1][2]); oa[1][2]=fmaf(a1.z,s2.z,oa[1][2]); oa[1][2]=fmaf(a1.w,s3.z,oa[1][2]);
          oa[1][3]=fmaf(a1.x,s0.w,oa[1][3]); oa[1][3]=fmaf(a1.y,s1.w,oa[1][3]); oa[1][3]=fmaf(a1.z,s2.w,oa[1][3]); oa[1][3]=fmaf(a1.w,s3.w,oa[1][3]);
          oa[2][0]=fmaf(a2.x,s0.x,oa[2][0]); oa[2][0]=fmaf(a2.y,s1.x,oa[2][0]); oa[2][0]=fmaf(a2.z,s2.x,oa[2][0]); oa[2][0]=fmaf(a2.w,s3.x,oa[2][0]);
          oa[2][1]=fmaf(a2.x,s0.y,oa[2][1]); oa[2][1]=fmaf(a2.y,s1.y,oa[2][1]); oa[2][1]=fmaf(a2.z,s2.y,oa[2][1]); oa[2][1]=fmaf(a2.w,s3.y,oa[2][1]);
          oa[2][2]=fmaf(a2.x,s0.z,oa[2][2]); oa[2][2]=fmaf(a2.y,s1.z,oa[2][2]); oa[2][2]=fmaf(a2.z,s2.z,oa[2][2]); oa[2][2]=fmaf(a2.w,s3.z,oa[2][2]);
          oa[2][3]=fmaf(a2.x,s0.w,oa[2][3]); oa[2][3]=fmaf(a2.y,s1.w,oa[2][3]); oa[2][3]=fmaf(a2.z,s2.w,oa[2][3]); oa[2][3]=fmaf(a2.w,s3.w,oa[2][3]);
          oa[3][0]=fmaf(a3.x,s0.x,oa[3][0]); oa[3][0]=fmaf(a3.y,s1.x,oa[3][0]); oa[3][0]=fmaf(a3.z,s2.x,oa[3][0]); oa[3][0]=fmaf(a3.w,s3.x,oa[3][0]);
          oa[3][1]=fmaf(a3.x,s0.y,oa[3][1]); oa[3][1]=fmaf(a3.y,s1.y,oa[3][1]); oa[3][1]=fmaf(a3.z,s2.y,oa[3][1]); oa[3][1]=fmaf(a3.w,s3.y,oa[3][1]);
          oa[3][2]=fmaf(a3.x,s0.z,oa[3][2]); oa[3][2]=fmaf(a3.y,s1.z,oa[3][2]); oa[3][2]=fmaf(a3.z,s2.z,oa[3][2]); oa[3][2]=fmaf(a3.w,s3.z,oa[3][2]);
          oa[3][3]=fmaf(a3.x,s0.w,oa[3][3]); oa[3][3]=fmaf(a3.y,s1.w,oa[3][3]); oa[3][3]=fmaf(a3.z,s2.w,oa[3][3]); oa[3][3]=fmaf(a3.w,s3.w,oa[3][3]);
        }
      }
      // update: S[b4] = gC*S[b4] + k~^T v (rows rq..rq+3, cols c0..c0+3)
#pragma unroll
      for (int ii = 0; ii < 4; ++ii) {
        S[b4][ii][0] *= gC; S[b4][ii][1] *= gC; S[b4][ii][2] *= gC; S[b4][ii][3] *= gC;
      }
      for (int j = 0; j < 64; ++j) {
        float4 kv = *(const float4*)&kS[j][rq];
        float4 vv = *(const float4*)&vS[j][c0];
        S[b4][0][0] = fmaf(kv.x, vv.x, S[b4][0][0]); S[b4][0][1] = fmaf(kv.x, vv.y, S[b4][0][1]);
        S[b4][0][2] = fmaf(kv.x, vv.z, S[b4][0][2]); S[b4][0][3] = fmaf(kv.x, vv.w, S[b4][0][3]);
        S[b4][1][0] = fmaf(kv.y, vv.x, S[b4][1][0]); S[b4][1][1] = fmaf(kv.y, vv.y, S[b4][1][1]);
        S[b4][1][2] = fmaf(kv.y, vv.z, S[b4][1][2]); S[b4][1][3] = fmaf(kv.y, vv.w, S[b4][1][3]);
        S[b4][2][0] = fmaf(kv.z, vv.x, S[b4][2][0]); S[b4][2][1] = fmaf(kv.z, vv.y, S[b4][2][1]);
        S[b4][2][2] = fmaf(kv.z, vv.z, S[b4][2][2]); S[b4][2][3] = fmaf(kv.z, vv.w, S[b4][2][3]);
        S[b4][3][0] = fmaf(kv.w, vv.x, S[b4][3][0]); S[b4][3][1] = fmaf(kv.w, vv.y, S[b4][3][1]);
        S[b4][3][2] = fmaf(kv.w, vv.z, S[b4][3][2]); S[b4][3][3] = fmaf(kv.w, vv.w, S[b4][3][3]);
      }
      __builtin_amdgcn_s_setprio(0);
    }
    // o += oa (skipped when S was all-zero: oa == 0)
    if (doO) {
#pragma unroll
      for (int ii = 0; ii < 4; ++ii) {
        size_t addr = baseV + (size_t)(t0 + i0 + ii) * VDIM + v0;
        float4 ov = *(const float4*)&o[addr];
        ov.x += oa[ii][0]; ov.y += oa[ii][1]; ov.z += oa[ii][2]; ov.w += oa[ii][3];
        *(float4*)&o[addr] = ov;
      }
    }
  }
}

// ------- RMS group-norm + SiLU(g) gate + bf16 hi/lo split (fused) ------------
__global__ __launch_bounds__(256) void norm_gate_cast(const float* __restrict__ o,
                                                      const float* __restrict__ g,
                                                      const float* __restrict__ gnw,
                                                      unsigned short* __restrict__ oh,
                                                      unsigned short* __restrict__ ol) {
  const int row = blockIdx.x;
  const size_t base = (size_t)row * 512;
  const int t = threadIdx.x;
  float x0 = o[base + t], x1 = o[base + t + 256];
  float ss = x0 * x0 + x1 * x1;
#pragma unroll
  for (int off = 32; off > 0; off >>= 1) ss += __shfl_down(ss, off, 64);
  __shared__ float wsum[4];
  if ((t & 63) == 0) wsum[t >> 6] = ss;
  __syncthreads();
  float tot = wsum[0] + wsum[1] + wsum[2] + wsum[3];
  float scale = rsqrtf(tot * (1.0f / 512.0f) + 1e-5f);
  float g0 = g[base + t], g1 = g[base + t + 256];
  float r0 = x0 * scale * gnw[t]       * (g0 / (1.0f + expf(-g0)));
  float r1 = x1 * scale * gnw[t + 256] * (g1 / (1.0f + expf(-g1)));
  unsigned short h0 = f2bf(r0);
  unsigned short h1 = f2bf(r1);
  oh[base + t]       = h0; ol[base + t]       = f2bf(r0 - bf2f(h0));
  oh[base + t + 256] = h1; ol[base + t + 256] = f2bf(r1 - bf2f(h1));
}

extern "C" void kernel_launch(void* const* d_in, const int* in_sizes, int n_in,
                              void* d_out, int out_size, void* d_ws, size_t ws_size,
                              hipStream_t stream) {
  const float* x   = (const float*)d_in[0];
  const float* Wq  = (const float*)d_in[1];
  const float* Wk  = (const float*)d_in[2];
  const float* Wv  = (const float*)d_in[3];
  const float* Wg  = (const float*)d_in[4];
  const float* Wo  = (const float*)d_in[5];
  const float* gnw = (const float*)d_in[6];
  float* out = (float*)d_out;

  // workspace = 256 MiB exactly:
  // [q 32][k 32][v 64][o 64][x-splits 32][W-splits 32]
  // o-splits (64) alias dead v; g (64) aliases dead q+k.
  // d_out (32 MiB): [0,24MiB) group-state scratch Tbuf; [24,26MiB) rope trig
  // table -- both dead before the final GEMM overwrites d_out.
  const size_t M8 = (size_t)8192;
  float* q  = (float*)d_ws;
  float* kk = q  + M8 * 1024;
  float* v  = kk + M8 * 1024;
  float* o  = v  + M8 * 2048;
  unsigned short* xh  = (unsigned short*)(o + M8 * 2048);
  unsigned short* xl  = xh  + M8 * 1024;
  unsigned short* wqh = xl  + M8 * 1024;
  unsigned short* wql = wqh + (size_t)1024 * 1024;
  unsigned short* wkh = wql + (size_t)1024 * 1024;
  unsigned short* wkl = wkh + (size_t)1024 * 1024;
  unsigned short* wvh = wkl + (size_t)1024 * 1024;
  unsigned short* wvl = wvh + (size_t)2048 * 1024;
  unsigned short* wgh = wvl + (size_t)2048 * 1024;
  unsigned short* wgl = wgh + (size_t)2048 * 1024;
  unsigned short* woh = wgl + (size_t)2048 * 1024;
  unsigned short* wol = woh + (size_t)2048 * 1024;
  unsigned short* oh  = (unsigned short*)v;
  unsigned short* ol  = oh + M8 * 2048;
  float* g = q;
  float* Tbuf = (float*)d_out;                       // 24 MiB scratch
  float2* rtab = (float2*)((float*)d_out + 6291456); // 2 MiB trig table

  dim3 blk(256);
  rope_tab<<<dim3(1024), blk, 0, stream>>>(rtab);
  cast_all<<<dim3(16384), blk, 0, stream>>>(x, Wq, Wk, Wv, Wg, Wo,
                                            xh, xl, wqh, wql, wkh, wkl,
                                            wvh, wvl, wgh, wgl, woh, wol);

  gemm_qkv<<<dim3(32, 64), blk, 0, stream>>>(xh, xl, wqh, wql, wkh, wkl, wvh, wvl, q, kk, v);
  rope_kernel<<<dim3(16384), blk, 0, stream>>>(q, kk, rtab);
  retn_gstate<<<dim3(16, 3, 8), blk, 0, stream>>>(kk, v, Tbuf);
  retn_scan<<<dim3(2048), blk, 0, stream>>>(Tbuf);
  retn_intra<<<dim3(32, 4, 4),  blk, 0, stream>>>(q, kk, v, o);
  retn_inter2<<<dim3(16, 4, 8), blk, 0, stream>>>(q, kk, v, o, Tbuf);
  gemm_bf16s<<<dim3(16, 64), blk, 0, stream>>>(xh, xl, wgh, wgl, g, 8192, 2048, 1024);
  norm_gate_cast<<<dim3(32768), blk, 0, stream>>>(o, g, gnw, oh, ol);
  gemm_bf16s<<<dim3(8, 64),  blk, 0, stream>>>(oh, ol, woh, wol, out, 8192, 1024, 2048);
}